// Round 1
// baseline (955.551 us; speedup 1.0000x reference)
//
#include <hip/hip_runtime.h>
#include <math.h>

#define NN 50000
#define EE 1600000
#define ETOT (EE + NN)
#define NEG_SLOPE 0.2f
#define BN_EPS 1e-5f

// ---------------- M[d,h] = sum_c We[d, h*32+c] * ae[h,c] (per layer) ----------------
__global__ void compute_M_k(const float* __restrict__ We1, const float* __restrict__ ae1,
                            const float* __restrict__ We2, const float* __restrict__ ae2,
                            const float* __restrict__ We3, const float* __restrict__ ae3,
                            float* __restrict__ M) {
  int t = threadIdx.x;
  if (t < 64) {
    int d = t >> 2, h = t & 3;
    float s1 = 0.f, s2 = 0.f;
    for (int c = 0; c < 32; ++c) {
      s1 += We1[d * 128 + h * 32 + c] * ae1[h * 32 + c];
      s2 += We2[d * 128 + h * 32 + c] * ae2[h * 32 + c];
    }
    M[t] = s1;
    M[64 + t] = s2;
  }
  if (t < 16) {
    M[128 + t] = We3[t * 2] * ae3[0] + We3[t * 2 + 1] * ae3[1];
  }
}

// -------- one pass over edge_attr: alpha_e for all 3 layers + mean accumulation --------
__global__ __launch_bounds__(256) void ea_pass_k(const float* __restrict__ ea,
                                                 const float* __restrict__ M,
                                                 float* __restrict__ ae1o,
                                                 float* __restrict__ ae2o,
                                                 float* __restrict__ ae3o,
                                                 float* __restrict__ mean_acc) {
  __shared__ float sM[144];
  __shared__ float smean[16];
  int t = threadIdx.x;
  if (t < 144) sM[t] = M[t];
  if (t < 16) smean[t] = 0.f;
  __syncthreads();
  int e = blockIdx.x * 256 + t;
  if (e < EE) {
    float v[16];
    const float4* p = (const float4*)(ea + (size_t)e * 16);
    float4 q0 = p[0], q1 = p[1], q2 = p[2], q3 = p[3];
    v[0] = q0.x; v[1] = q0.y; v[2] = q0.z; v[3] = q0.w;
    v[4] = q1.x; v[5] = q1.y; v[6] = q1.z; v[7] = q1.w;
    v[8] = q2.x; v[9] = q2.y; v[10] = q2.z; v[11] = q2.w;
    v[12] = q3.x; v[13] = q3.y; v[14] = q3.z; v[15] = q3.w;
#pragma unroll
    for (int h = 0; h < 4; ++h) {
      float s = 0.f;
#pragma unroll
      for (int d = 0; d < 16; ++d) s += v[d] * sM[d * 4 + h];
      ae1o[(size_t)e * 4 + h] = s;
    }
#pragma unroll
    for (int h = 0; h < 4; ++h) {
      float s = 0.f;
#pragma unroll
      for (int d = 0; d < 16; ++d) s += v[d] * sM[64 + d * 4 + h];
      ae2o[(size_t)e * 4 + h] = s;
    }
    float s3 = 0.f;
#pragma unroll
    for (int d = 0; d < 16; ++d) s3 += v[d] * sM[128 + d];
    ae3o[e] = s3;
#pragma unroll
    for (int d = 0; d < 16; ++d) atomicAdd(&smean[d], v[d]);
  }
  __syncthreads();
  if (t < 16) atomicAdd(&mean_acc[t], smean[t]);
}

// -------- self-loop alpha_e scalars: alpha_sl[0..3]=L1, [4..7]=L2, [8]=L3 --------
__global__ void selfloop_k(const float* __restrict__ mean_acc, const float* __restrict__ M,
                           float* __restrict__ alpha_sl) {
  int t = threadIdx.x;
  if (t < 9) {
    float s = 0.f;
    if (t < 4) {
      for (int d = 0; d < 16; ++d) s += (mean_acc[d] / (float)EE) * M[d * 4 + t];
    } else if (t < 8) {
      int h = t - 4;
      for (int d = 0; d < 16; ++d) s += (mean_acc[d] / (float)EE) * M[64 + d * 4 + h];
    } else {
      for (int d = 0; d < 16; ++d) s += (mean_acc[d] / (float)EE) * M[128 + d];
    }
    alpha_sl[t] = s;
  }
}

// ---------------- CSR build ----------------
__global__ void deg_k(const int* __restrict__ dst, int* __restrict__ deg) {
  int e = blockIdx.x * blockDim.x + threadIdx.x;
  if (e < ETOT) {
    int d = (e < EE) ? dst[e] : (e - EE);
    atomicAdd(&deg[d], 1);
  }
}

__global__ __launch_bounds__(1024) void scan_k(const int* __restrict__ deg,
                                               int* __restrict__ row_ofs,
                                               int* __restrict__ cursor) {
  __shared__ int ssum[1024];
  int t = threadIdx.x;
  const int CH = (NN + 1023) / 1024;
  int beg = t * CH;
  int end = beg + CH; if (end > NN) end = NN; if (beg > NN) beg = NN;
  int s = 0;
  for (int i = beg; i < end; ++i) s += deg[i];
  ssum[t] = s;
  __syncthreads();
  for (int off = 1; off < 1024; off <<= 1) {
    int v = (t >= off) ? ssum[t - off] : 0;
    __syncthreads();
    ssum[t] += v;
    __syncthreads();
  }
  int run = ssum[t] - s;  // exclusive prefix of this thread's chunk
  for (int i = beg; i < end; ++i) {
    row_ofs[i] = run;
    cursor[i] = run;
    run += deg[i];
  }
  if (end == NN) row_ofs[NN] = run;  // all such threads write the same total
}

__global__ void fill_k(const int* __restrict__ src, const int* __restrict__ dst,
                       int* __restrict__ cursor, int* __restrict__ csr_src,
                       int* __restrict__ csr_eid) {
  int e = blockIdx.x * blockDim.x + threadIdx.x;
  if (e < ETOT) {
    int d = (e < EE) ? dst[e] : (e - EE);
    int s = (e < EE) ? src[e] : (e - EE);
    int pos = atomicAdd(&cursor[d], 1);
    csr_src[pos] = s;
    csr_eid[pos] = e;
  }
}

// ---------------- f32 GEMM: Y[N,128] = X[N,128] @ W[128,128], LDS tiled ----------------
__global__ __launch_bounds__(256) void gemm128_k(const float* __restrict__ X,
                                                 const float* __restrict__ W,
                                                 float* __restrict__ Y, int nrows) {
  __shared__ float sW[128 * 128];
  __shared__ float sX[64 * 128];
  int t = threadIdx.x;
  int r0 = blockIdx.x * 64;
  {
    const float4* w4 = (const float4*)W;
    float4* s4 = (float4*)sW;
#pragma unroll
    for (int i = 0; i < 16; ++i) s4[t + i * 256] = w4[t + i * 256];
  }
  {
    int rows = nrows - r0; if (rows > 64) rows = 64;
    int maxv = rows * 32;  // float4 count
    const float4* x4 = (const float4*)(X + (size_t)r0 * 128);
    float4* s4 = (float4*)sX;
#pragma unroll
    for (int i = 0; i < 8; ++i) {
      int idx = t + i * 256;
      if (idx < maxv) s4[idx] = x4[idx];
    }
  }
  __syncthreads();
  int cq = t & 31;   // 4 cols: cq*4..cq*4+3
  int rl = t >> 5;   // rows rl, rl+8, ..., rl+56
  float acc[8][4];
#pragma unroll
  for (int i = 0; i < 8; ++i)
#pragma unroll
    for (int j = 0; j < 4; ++j) acc[i][j] = 0.f;

  for (int k = 0; k < 128; k += 4) {
    float4 w0 = *(float4*)&sW[(k + 0) * 128 + cq * 4];
    float4 w1 = *(float4*)&sW[(k + 1) * 128 + cq * 4];
    float4 w2 = *(float4*)&sW[(k + 2) * 128 + cq * 4];
    float4 w3 = *(float4*)&sW[(k + 3) * 128 + cq * 4];
#pragma unroll
    for (int i = 0; i < 8; ++i) {
      float4 xv = *(float4*)&sX[(rl + i * 8) * 128 + k];
      acc[i][0] += xv.x * w0.x + xv.y * w1.x + xv.z * w2.x + xv.w * w3.x;
      acc[i][1] += xv.x * w0.y + xv.y * w1.y + xv.z * w2.y + xv.w * w3.y;
      acc[i][2] += xv.x * w0.z + xv.y * w1.z + xv.z * w2.z + xv.w * w3.z;
      acc[i][3] += xv.x * w0.w + xv.y * w1.w + xv.z * w2.w + xv.w * w3.w;
    }
  }
#pragma unroll
  for (int i = 0; i < 8; ++i) {
    int r = r0 + rl + i * 8;
    if (r < nrows) {
      float4 o; o.x = acc[i][0]; o.y = acc[i][1]; o.z = acc[i][2]; o.w = acc[i][3];
      *(float4*)&Y[(size_t)r * 128 + cq * 4] = o;
    }
  }
}

// ---------------- alpha_src/alpha_dst per (node, head) ----------------
__global__ __launch_bounds__(256) void node_alpha_k(const float* __restrict__ xp,
                                                    const float* __restrict__ as,
                                                    const float* __restrict__ ad,
                                                    float* __restrict__ asrc,
                                                    float* __restrict__ adst) {
  __shared__ float sas[128], sad[128];
  int t = threadIdx.x;
  if (t < 128) { sas[t] = as[t]; sad[t] = ad[t]; }
  __syncthreads();
  int gid = blockIdx.x * 256 + t;
  if (gid < NN * 4) {
    int n = gid >> 2, h = gid & 3;
    const float4* row = (const float4*)(xp + (size_t)n * 128 + h * 32);
    const float4* a4 = (const float4*)(sas + h * 32);
    const float4* d4 = (const float4*)(sad + h * 32);
    float s1 = 0.f, s2 = 0.f;
#pragma unroll
    for (int i = 0; i < 8; ++i) {
      float4 v = row[i], a = a4[i], d = d4[i];
      s1 += v.x * a.x + v.y * a.y + v.z * a.z + v.w * a.w;
      s2 += v.x * d.x + v.y * d.y + v.z * d.z + v.w * d.w;
    }
    asrc[gid] = s1;
    adst[gid] = s2;
  }
}

// ------- per-node aggregation, H=4 C=32, online softmax, fused bias+BN+ELU -------
__global__ __launch_bounds__(128) void agg128_k(
    const int* __restrict__ row_ofs, const int* __restrict__ csr_src,
    const int* __restrict__ csr_eid, const float* __restrict__ xp,
    const float* __restrict__ asrc, const float* __restrict__ adst,
    const float* __restrict__ ae, const float* __restrict__ alpha_sl,
    const float* __restrict__ bias, const float* __restrict__ g,
    const float* __restrict__ be, const float* __restrict__ rm,
    const float* __restrict__ rv, float* __restrict__ out) {
  int n = blockIdx.x;
  int t = threadIdx.x;
  int h = t >> 5;   // head (also the head this thread's alpha work covers)
  int j = t & 31;   // edge slot within chunk / channel within head
  __shared__ float s_w[4 * 32];  // [head][edge]
  __shared__ int s_src[32];
  int beg = row_ofs[n], end = row_ofs[n + 1];
  float adn = adst[n * 4 + h];
  float asl = alpha_sl[h];
  float m_run = -1e30f, s_run = 0.f, acc = 0.f;

  for (int base = beg; base < end; base += 32) {
    int cnt = end - base; if (cnt > 32) cnt = 32;
    float a = -1e30f;
    if (j < cnt) {
      int idx = base + j;
      int sj = csr_src[idx];
      int eid = csr_eid[idx];
      float aev = (eid < EE) ? ae[(size_t)eid * 4 + h] : asl;
      a = asrc[sj * 4 + h] + adn + aev;
      a = (a > 0.f) ? a : NEG_SLOPE * a;
      if (h == 0) s_src[j] = sj;
    }
    // chunk max per head (32-lane group reduce; identical in all lanes of group)
    float cm = a;
#pragma unroll
    for (int off = 16; off; off >>= 1) cm = fmaxf(cm, __shfl_xor(cm, off, 32));
    if (cm > m_run) {
      float f = expf(m_run - cm);
      s_run *= f; acc *= f; m_run = cm;
    }
    float ex = 0.f;
    if (j < cnt) ex = expf(a - m_run);
    s_w[h * 32 + j] = ex;
    float se = ex;
#pragma unroll
    for (int off = 16; off; off >>= 1) se += __shfl_xor(se, off, 32);
    s_run += se;
    __syncthreads();
    // accumulate messages: all 128 threads stream xp rows (coalesced 512B)
    int e2 = 0;
    for (; e2 + 4 <= cnt; e2 += 4) {
      float w0 = s_w[h * 32 + e2 + 0];
      float w1 = s_w[h * 32 + e2 + 1];
      float w2 = s_w[h * 32 + e2 + 2];
      float w3 = s_w[h * 32 + e2 + 3];
      float x0 = xp[(size_t)s_src[e2 + 0] * 128 + t];
      float x1 = xp[(size_t)s_src[e2 + 1] * 128 + t];
      float x2 = xp[(size_t)s_src[e2 + 2] * 128 + t];
      float x3 = xp[(size_t)s_src[e2 + 3] * 128 + t];
      acc += w0 * x0 + w1 * x1 + w2 * x2 + w3 * x3;
    }
    for (; e2 < cnt; ++e2) {
      acc += s_w[h * 32 + e2] * xp[(size_t)s_src[e2] * 128 + t];
    }
    __syncthreads();
  }
  float v = acc / (s_run + 1e-16f) + bias[t];
  // BN (eval) + ELU
  v = (v - rm[t]) * (g[t] * rsqrtf(rv[t] + BN_EPS)) + be[t];
  v = (v > 0.f) ? v : (expf(v) - 1.f);
  out[(size_t)n * 128 + t] = v;
}

// ---------------- layer 3 projection + alphas: xp3[N,2], asrc3, adst3 ----------------
__global__ __launch_bounds__(256) void xp3_k(const float* __restrict__ h2,
                                             const float* __restrict__ W3,
                                             const float* __restrict__ as3,
                                             const float* __restrict__ ad3,
                                             float* __restrict__ xp3,
                                             float* __restrict__ asrc3,
                                             float* __restrict__ adst3) {
  __shared__ float sW[256];
  int t = threadIdx.x;
  sW[t] = W3[t];
  __syncthreads();
  int n = blockIdx.x * 256 + t;
  if (n < NN) {
    const float4* row = (const float4*)(h2 + (size_t)n * 128);
    float y0 = 0.f, y1 = 0.f;
#pragma unroll
    for (int i = 0; i < 32; ++i) {
      float4 v = row[i];
      y0 += v.x * sW[(i * 4 + 0) * 2] + v.y * sW[(i * 4 + 1) * 2] +
            v.z * sW[(i * 4 + 2) * 2] + v.w * sW[(i * 4 + 3) * 2];
      y1 += v.x * sW[(i * 4 + 0) * 2 + 1] + v.y * sW[(i * 4 + 1) * 2 + 1] +
            v.z * sW[(i * 4 + 2) * 2 + 1] + v.w * sW[(i * 4 + 3) * 2 + 1];
    }
    xp3[n * 2] = y0;
    xp3[n * 2 + 1] = y1;
    asrc3[n] = y0 * as3[0] + y1 * as3[1];
    adst3[n] = y0 * ad3[0] + y1 * ad3[1];
  }
}

// ---------------- layer 3 aggregation: wave per node, 1 head, 2 channels ----------------
__global__ __launch_bounds__(256) void agg2_k(const int* __restrict__ row_ofs,
                                              const int* __restrict__ csr_src,
                                              const int* __restrict__ csr_eid,
                                              const float* __restrict__ xp3,
                                              const float* __restrict__ asrc3,
                                              const float* __restrict__ adst3,
                                              const float* __restrict__ ae3,
                                              const float* __restrict__ alpha_sl,
                                              const float* __restrict__ b3,
                                              float* __restrict__ out) {
  int t = threadIdx.x;
  int w = t >> 6, l = t & 63;
  int n = blockIdx.x * 4 + w;
  if (n >= NN) return;
  int beg = row_ofs[n], end = row_ofs[n + 1];
  float adn = adst3[n];
  float asl = alpha_sl[0];
  float m = -1e30f, s = 0.f, a0 = 0.f, a1 = 0.f;
  for (int idx = beg + l; idx < end; idx += 64) {
    int sj = csr_src[idx];
    int eid = csr_eid[idx];
    float aev = (eid < EE) ? ae3[eid] : asl;
    float a = asrc3[sj] + adn + aev;
    a = (a > 0.f) ? a : NEG_SLOPE * a;
    if (a > m) {
      float f = expf(m - a);
      s *= f; a0 *= f; a1 *= f; m = a;
    }
    float ex = expf(a - m);
    s += ex;
    a0 += ex * xp3[sj * 2];
    a1 += ex * xp3[sj * 2 + 1];
  }
  float M = m;
#pragma unroll
  for (int off = 32; off; off >>= 1) M = fmaxf(M, __shfl_xor(M, off, 64));
  float f = expf(m - M);  // m=-1e30 (idle lane) -> 0
  s *= f; a0 *= f; a1 *= f;
#pragma unroll
  for (int off = 32; off; off >>= 1) {
    s += __shfl_xor(s, off, 64);
    a0 += __shfl_xor(a0, off, 64);
    a1 += __shfl_xor(a1, off, 64);
  }
  if (l == 0) {
    float inv = 1.f / (s + 1e-16f);
    out[n * 2] = a0 * inv + b3[0];
    out[n * 2 + 1] = a1 * inv + b3[1];
  }
}

// ---------------- launcher ----------------
extern "C" void kernel_launch(void* const* d_in, const int* in_sizes, int n_in,
                              void* d_out, int out_size, void* d_ws, size_t ws_size,
                              hipStream_t stream) {
  const float* x   = (const float*)d_in[0];
  const int*   ei  = (const int*)d_in[1];
  const float* ea  = (const float*)d_in[2];
  const float* W1  = (const float*)d_in[3];
  const float* as1 = (const float*)d_in[4];
  const float* ad1 = (const float*)d_in[5];
  const float* We1 = (const float*)d_in[6];
  const float* ae1 = (const float*)d_in[7];
  const float* b1  = (const float*)d_in[8];
  const float* g1  = (const float*)d_in[9];
  const float* be1 = (const float*)d_in[10];
  const float* rm1 = (const float*)d_in[11];
  const float* rv1 = (const float*)d_in[12];
  const float* W2  = (const float*)d_in[13];
  const float* as2 = (const float*)d_in[14];
  const float* ad2 = (const float*)d_in[15];
  const float* We2 = (const float*)d_in[16];
  const float* ae2 = (const float*)d_in[17];
  const float* b2  = (const float*)d_in[18];
  const float* g2  = (const float*)d_in[19];
  const float* be2 = (const float*)d_in[20];
  const float* rm2 = (const float*)d_in[21];
  const float* rv2 = (const float*)d_in[22];
  const float* W3  = (const float*)d_in[23];
  const float* as3 = (const float*)d_in[24];
  const float* ad3 = (const float*)d_in[25];
  const float* We3 = (const float*)d_in[26];
  const float* ae3 = (const float*)d_in[27];
  const float* b3  = (const float*)d_in[28];

  const int* srcA = ei;
  const int* dstA = ei + EE;

  char* p = (char*)d_ws;
  auto alloc = [&](size_t bytes) -> void* {
    void* r = (void*)p;
    p += (bytes + 255) & ~(size_t)255;
    return r;
  };
  float* xp    = (float*)alloc(sizeof(float) * (size_t)NN * 128);
  float* hbuf  = (float*)alloc(sizeof(float) * (size_t)NN * 128);
  float* ae1o  = (float*)alloc(sizeof(float) * (size_t)EE * 4);
  float* ae2o  = (float*)alloc(sizeof(float) * (size_t)EE * 4);
  float* ae3o  = (float*)alloc(sizeof(float) * (size_t)EE);
  float* Mbuf  = (float*)alloc(sizeof(float) * 144);
  float* meanb = (float*)alloc(sizeof(float) * 16);
  float* asl   = (float*)alloc(sizeof(float) * 9);
  float* asrc  = (float*)alloc(sizeof(float) * (size_t)NN * 4);
  float* adst  = (float*)alloc(sizeof(float) * (size_t)NN * 4);
  float* xp3   = (float*)alloc(sizeof(float) * (size_t)NN * 2);
  float* asrc3 = (float*)alloc(sizeof(float) * (size_t)NN);
  float* adst3 = (float*)alloc(sizeof(float) * (size_t)NN);
  int* deg     = (int*)alloc(sizeof(int) * (size_t)NN);
  int* row_ofs = (int*)alloc(sizeof(int) * (size_t)(NN + 1));
  int* cursor  = (int*)alloc(sizeof(int) * (size_t)NN);
  int* csr_src = (int*)alloc(sizeof(int) * (size_t)ETOT);
  int* csr_eid = (int*)alloc(sizeof(int) * (size_t)ETOT);

  hipMemsetAsync(meanb, 0, 16 * sizeof(float), stream);
  hipMemsetAsync(deg, 0, NN * sizeof(int), stream);

  compute_M_k<<<1, 64, 0, stream>>>(We1, ae1, We2, ae2, We3, ae3, Mbuf);
  ea_pass_k<<<(EE + 255) / 256, 256, 0, stream>>>(ea, Mbuf, ae1o, ae2o, ae3o, meanb);
  selfloop_k<<<1, 64, 0, stream>>>(meanb, Mbuf, asl);
  deg_k<<<(ETOT + 255) / 256, 256, 0, stream>>>(dstA, deg);
  scan_k<<<1, 1024, 0, stream>>>(deg, row_ofs, cursor);
  fill_k<<<(ETOT + 255) / 256, 256, 0, stream>>>(srcA, dstA, cursor, csr_src, csr_eid);

  // ---- layer 1 ----
  gemm128_k<<<(NN + 63) / 64, 256, 0, stream>>>(x, W1, xp, NN);
  node_alpha_k<<<(NN * 4 + 255) / 256, 256, 0, stream>>>(xp, as1, ad1, asrc, adst);
  agg128_k<<<NN, 128, 0, stream>>>(row_ofs, csr_src, csr_eid, xp, asrc, adst,
                                   ae1o, asl, b1, g1, be1, rm1, rv1, hbuf);
  // ---- layer 2 ----
  gemm128_k<<<(NN + 63) / 64, 256, 0, stream>>>(hbuf, W2, xp, NN);
  node_alpha_k<<<(NN * 4 + 255) / 256, 256, 0, stream>>>(xp, as2, ad2, asrc, adst);
  agg128_k<<<NN, 128, 0, stream>>>(row_ofs, csr_src, csr_eid, xp, asrc, adst,
                                   ae2o, asl + 4, b2, g2, be2, rm2, rv2, hbuf);
  // ---- layer 3 ----
  xp3_k<<<(NN + 255) / 256, 256, 0, stream>>>(hbuf, W3, as3, ad3, xp3, asrc3, adst3);
  agg2_k<<<(NN + 3) / 4, 256, 0, stream>>>(row_ofs, csr_src, csr_eid, xp3, asrc3,
                                           adst3, ae3o, asl + 8, b3, (float*)d_out);
}

// Round 2
// 689.086 us; speedup vs baseline: 1.3867x; 1.3867x over previous
//
#include <hip/hip_runtime.h>
#include <math.h>

#define NN 50000
#define EE 1600000
#define ETOT (EE + NN)
#define NEG_SLOPE 0.2f
#define BN_EPS 1e-5f
#define EA_BLOCKS 1024
#define NB_SCAN ((NN + 255) / 256)

// ---------------- M[d,h] = sum_c We[d, h*32+c] * ae[h,c] (per layer) ----------------
__global__ void compute_M_k(const float* __restrict__ We1, const float* __restrict__ ae1,
                            const float* __restrict__ We2, const float* __restrict__ ae2,
                            const float* __restrict__ We3, const float* __restrict__ ae3,
                            float* __restrict__ M) {
  int t = threadIdx.x;
  if (t < 64) {
    int d = t >> 2, h = t & 3;
    float s1 = 0.f, s2 = 0.f;
    for (int c = 0; c < 32; ++c) {
      s1 += We1[d * 128 + h * 32 + c] * ae1[h * 32 + c];
      s2 += We2[d * 128 + h * 32 + c] * ae2[h * 32 + c];
    }
    M[t] = s1;
    M[64 + t] = s2;
  }
  if (t < 16) {
    M[128 + t] = We3[t * 2] * ae3[0] + We3[t * 2 + 1] * ae3[1];
  }
}

// -------- one pass over edge_attr: alpha_e for all 3 layers + per-block mean partials --------
__global__ __launch_bounds__(256) void ea_pass_k(const float* __restrict__ ea,
                                                 const float* __restrict__ M,
                                                 float* __restrict__ ae1o,
                                                 float* __restrict__ ae2o,
                                                 float* __restrict__ ae3o,
                                                 float* __restrict__ mean_part) {
  __shared__ float sM[144];
  int t = threadIdx.x;
  if (t < 144) sM[t] = M[t];
  __syncthreads();
  float macc[16];
#pragma unroll
  for (int d = 0; d < 16; ++d) macc[d] = 0.f;

  for (int e = blockIdx.x * 256 + t; e < EE; e += EA_BLOCKS * 256) {
    float v[16];
    const float4* p = (const float4*)(ea + (size_t)e * 16);
    float4 q0 = p[0], q1 = p[1], q2 = p[2], q3 = p[3];
    v[0] = q0.x; v[1] = q0.y; v[2] = q0.z; v[3] = q0.w;
    v[4] = q1.x; v[5] = q1.y; v[6] = q1.z; v[7] = q1.w;
    v[8] = q2.x; v[9] = q2.y; v[10] = q2.z; v[11] = q2.w;
    v[12] = q3.x; v[13] = q3.y; v[14] = q3.z; v[15] = q3.w;
#pragma unroll
    for (int h = 0; h < 4; ++h) {
      float s = 0.f;
#pragma unroll
      for (int d = 0; d < 16; ++d) s += v[d] * sM[d * 4 + h];
      ae1o[(size_t)e * 4 + h] = s;
    }
#pragma unroll
    for (int h = 0; h < 4; ++h) {
      float s = 0.f;
#pragma unroll
      for (int d = 0; d < 16; ++d) s += v[d] * sM[64 + d * 4 + h];
      ae2o[(size_t)e * 4 + h] = s;
    }
    float s3 = 0.f;
#pragma unroll
    for (int d = 0; d < 16; ++d) s3 += v[d] * sM[128 + d];
    ae3o[e] = s3;
#pragma unroll
    for (int d = 0; d < 16; ++d) macc[d] += v[d];
  }
  // wave reduce each dim, then cross-wave via LDS, one global write per block
#pragma unroll
  for (int d = 0; d < 16; ++d) {
#pragma unroll
    for (int off = 32; off; off >>= 1) macc[d] += __shfl_xor(macc[d], off, 64);
  }
  __shared__ float swsum[4][16];
  int w = t >> 6, l = t & 63;
  if (l == 0) {
#pragma unroll
    for (int d = 0; d < 16; ++d) swsum[w][d] = macc[d];
  }
  __syncthreads();
  if (t < 16) {
    mean_part[(size_t)blockIdx.x * 16 + t] =
        swsum[0][t] + swsum[1][t] + swsum[2][t] + swsum[3][t];
  }
}

// -------- reduce mean partials + self-loop alpha_e: alpha_sl[0..3]=L1, [4..7]=L2, [8]=L3 --------
__global__ __launch_bounds__(256) void selfloop_k(const float* __restrict__ mean_part,
                                                  const float* __restrict__ M,
                                                  float* __restrict__ alpha_sl) {
  __shared__ float s[256];
  int t = threadIdx.x;
  int d = t & 15, c = t >> 4;  // 16 chunks of 64 blocks
  float v = 0.f;
  for (int i = c * 64; i < (c + 1) * 64; ++i) v += mean_part[(size_t)i * 16 + d];
  s[t] = v;
  __syncthreads();
  if (t < 16) {
    float sum = 0.f;
    for (int c2 = 0; c2 < 16; ++c2) sum += s[c2 * 16 + t];
    s[t] = sum / (float)EE;  // mean vector
  }
  __syncthreads();
  if (t < 9) {
    float r = 0.f;
    if (t < 4) {
      for (int dd = 0; dd < 16; ++dd) r += s[dd] * M[dd * 4 + t];
    } else if (t < 8) {
      int h = t - 4;
      for (int dd = 0; dd < 16; ++dd) r += s[dd] * M[64 + dd * 4 + h];
    } else {
      for (int dd = 0; dd < 16; ++dd) r += s[dd] * M[128 + dd];
    }
    alpha_sl[t] = r;
  }
}

// ---------------- CSR build ----------------
__global__ void deg_k(const int* __restrict__ dst, int* __restrict__ deg) {
  int e = blockIdx.x * blockDim.x + threadIdx.x;
  if (e < ETOT) {
    int d = (e < EE) ? dst[e] : (e - EE);
    atomicAdd(&deg[d], 1);
  }
}

// hierarchical scan: block partials -> scan partials -> per-block fill
__global__ __launch_bounds__(256) void scan_part_k(const int* __restrict__ deg,
                                                   int* __restrict__ part) {
  int t = threadIdx.x;
  int i = blockIdx.x * 256 + t;
  int v = (i < NN) ? deg[i] : 0;
#pragma unroll
  for (int off = 32; off; off >>= 1) v += __shfl_xor(v, off, 64);
  __shared__ int s[4];
  if ((t & 63) == 0) s[t >> 6] = v;
  __syncthreads();
  if (t == 0) part[blockIdx.x] = s[0] + s[1] + s[2] + s[3];
}

__global__ __launch_bounds__(256) void scan_base_k(int* __restrict__ part) {
  __shared__ int s[256];
  int t = threadIdx.x;
  int v = (t < NB_SCAN) ? part[t] : 0;
  s[t] = v;
  __syncthreads();
  for (int off = 1; off < 256; off <<= 1) {
    int u = (t >= off) ? s[t - off] : 0;
    __syncthreads();
    s[t] += u;
    __syncthreads();
  }
  if (t < NB_SCAN) part[t] = s[t] - v;  // exclusive block base
}

__global__ __launch_bounds__(256) void scan_fill_k(const int* __restrict__ deg,
                                                   const int* __restrict__ part,
                                                   int* __restrict__ row_ofs,
                                                   int* __restrict__ cursor) {
  __shared__ int s[256];
  int t = threadIdx.x;
  int i = blockIdx.x * 256 + t;
  int v = (i < NN) ? deg[i] : 0;
  s[t] = v;
  __syncthreads();
  for (int off = 1; off < 256; off <<= 1) {
    int u = (t >= off) ? s[t - off] : 0;
    __syncthreads();
    s[t] += u;
    __syncthreads();
  }
  int excl = s[t] - v + part[blockIdx.x];
  if (i < NN) {
    row_ofs[i] = excl;
    cursor[i] = excl;
  }
  if (i == NN - 1) row_ofs[NN] = ETOT;
}

__global__ void fill_k(const int* __restrict__ src, const int* __restrict__ dst,
                       int* __restrict__ cursor, int* __restrict__ csr_src,
                       int* __restrict__ csr_eid) {
  int e = blockIdx.x * blockDim.x + threadIdx.x;
  if (e < ETOT) {
    int d = (e < EE) ? dst[e] : (e - EE);
    int s = (e < EE) ? src[e] : (e - EE);
    int pos = atomicAdd(&cursor[d], 1);
    csr_src[pos] = s;
    csr_eid[pos] = e;
  }
}

// ---------------- f32 GEMM: Y[N,128] = X[N,128] @ W[128,128], LDS tiled ----------------
__global__ __launch_bounds__(256) void gemm128_k(const float* __restrict__ X,
                                                 const float* __restrict__ W,
                                                 float* __restrict__ Y, int nrows) {
  __shared__ float sW[128 * 128];
  __shared__ float sX[64 * 128];
  int t = threadIdx.x;
  int r0 = blockIdx.x * 64;
  {
    const float4* w4 = (const float4*)W;
    float4* s4 = (float4*)sW;
#pragma unroll
    for (int i = 0; i < 16; ++i) s4[t + i * 256] = w4[t + i * 256];
  }
  {
    int rows = nrows - r0; if (rows > 64) rows = 64;
    int maxv = rows * 32;  // float4 count
    const float4* x4 = (const float4*)(X + (size_t)r0 * 128);
    float4* s4 = (float4*)sX;
#pragma unroll
    for (int i = 0; i < 8; ++i) {
      int idx = t + i * 256;
      if (idx < maxv) s4[idx] = x4[idx];
    }
  }
  __syncthreads();
  int cq = t & 31;   // 4 cols: cq*4..cq*4+3
  int rl = t >> 5;   // rows rl, rl+8, ..., rl+56
  float acc[8][4];
#pragma unroll
  for (int i = 0; i < 8; ++i)
#pragma unroll
    for (int j = 0; j < 4; ++j) acc[i][j] = 0.f;

  for (int k = 0; k < 128; k += 4) {
    float4 w0 = *(float4*)&sW[(k + 0) * 128 + cq * 4];
    float4 w1 = *(float4*)&sW[(k + 1) * 128 + cq * 4];
    float4 w2 = *(float4*)&sW[(k + 2) * 128 + cq * 4];
    float4 w3 = *(float4*)&sW[(k + 3) * 128 + cq * 4];
#pragma unroll
    for (int i = 0; i < 8; ++i) {
      float4 xv = *(float4*)&sX[(rl + i * 8) * 128 + k];
      acc[i][0] += xv.x * w0.x + xv.y * w1.x + xv.z * w2.x + xv.w * w3.x;
      acc[i][1] += xv.x * w0.y + xv.y * w1.y + xv.z * w2.y + xv.w * w3.y;
      acc[i][2] += xv.x * w0.z + xv.y * w1.z + xv.z * w2.z + xv.w * w3.z;
      acc[i][3] += xv.x * w0.w + xv.y * w1.w + xv.z * w2.w + xv.w * w3.w;
    }
  }
#pragma unroll
  for (int i = 0; i < 8; ++i) {
    int r = r0 + rl + i * 8;
    if (r < nrows) {
      float4 o; o.x = acc[i][0]; o.y = acc[i][1]; o.z = acc[i][2]; o.w = acc[i][3];
      *(float4*)&Y[(size_t)r * 128 + cq * 4] = o;
    }
  }
}

// ---------------- alpha_src/alpha_dst per (node, head) ----------------
__global__ __launch_bounds__(256) void node_alpha_k(const float* __restrict__ xp,
                                                    const float* __restrict__ as,
                                                    const float* __restrict__ ad,
                                                    float* __restrict__ asrc,
                                                    float* __restrict__ adst) {
  __shared__ float sas[128], sad[128];
  int t = threadIdx.x;
  if (t < 128) { sas[t] = as[t]; sad[t] = ad[t]; }
  __syncthreads();
  int gid = blockIdx.x * 256 + t;
  if (gid < NN * 4) {
    int n = gid >> 2, h = gid & 3;
    const float4* row = (const float4*)(xp + (size_t)n * 128 + h * 32);
    const float4* a4 = (const float4*)(sas + h * 32);
    const float4* d4 = (const float4*)(sad + h * 32);
    float s1 = 0.f, s2 = 0.f;
#pragma unroll
    for (int i = 0; i < 8; ++i) {
      float4 v = row[i], a = a4[i], d = d4[i];
      s1 += v.x * a.x + v.y * a.y + v.z * a.z + v.w * a.w;
      s2 += v.x * d.x + v.y * d.y + v.z * d.z + v.w * d.w;
    }
    asrc[gid] = s1;
    adst[gid] = s2;
  }
}

// ------- per-node aggregation, H=4 C=32, online softmax, fused bias+BN+ELU -------
__global__ __launch_bounds__(128) void agg128_k(
    const int* __restrict__ row_ofs, const int* __restrict__ csr_src,
    const int* __restrict__ csr_eid, const float* __restrict__ xp,
    const float* __restrict__ asrc, const float* __restrict__ adst,
    const float* __restrict__ ae, const float* __restrict__ alpha_sl,
    const float* __restrict__ bias, const float* __restrict__ g,
    const float* __restrict__ be, const float* __restrict__ rm,
    const float* __restrict__ rv, float* __restrict__ out) {
  int n = blockIdx.x;
  int t = threadIdx.x;
  int h = t >> 5;   // head (also the head this thread's alpha work covers)
  int j = t & 31;   // edge slot within chunk / channel within head
  __shared__ float s_w[4 * 32];  // [head][edge]
  __shared__ int s_src[32];
  int beg = row_ofs[n], end = row_ofs[n + 1];
  float adn = adst[n * 4 + h];
  float asl = alpha_sl[h];
  float m_run = -1e30f, s_run = 0.f, acc = 0.f;

  for (int base = beg; base < end; base += 32) {
    int cnt = end - base; if (cnt > 32) cnt = 32;
    float a = -1e30f;
    if (j < cnt) {
      int idx = base + j;
      int sj = csr_src[idx];
      int eid = csr_eid[idx];
      float aev = (eid < EE) ? ae[(size_t)eid * 4 + h] : asl;
      a = asrc[sj * 4 + h] + adn + aev;
      a = (a > 0.f) ? a : NEG_SLOPE * a;
      if (h == 0) s_src[j] = sj;
    }
    // chunk max per head (32-lane group reduce; identical in all lanes of group)
    float cm = a;
#pragma unroll
    for (int off = 16; off; off >>= 1) cm = fmaxf(cm, __shfl_xor(cm, off, 32));
    if (cm > m_run) {
      float f = expf(m_run - cm);
      s_run *= f; acc *= f; m_run = cm;
    }
    float ex = 0.f;
    if (j < cnt) ex = expf(a - m_run);
    s_w[h * 32 + j] = ex;
    float se = ex;
#pragma unroll
    for (int off = 16; off; off >>= 1) se += __shfl_xor(se, off, 32);
    s_run += se;
    __syncthreads();
    // accumulate messages: all 128 threads stream xp rows (coalesced 512B)
    int e2 = 0;
    for (; e2 + 4 <= cnt; e2 += 4) {
      float w0 = s_w[h * 32 + e2 + 0];
      float w1 = s_w[h * 32 + e2 + 1];
      float w2 = s_w[h * 32 + e2 + 2];
      float w3 = s_w[h * 32 + e2 + 3];
      float x0 = xp[(size_t)s_src[e2 + 0] * 128 + t];
      float x1 = xp[(size_t)s_src[e2 + 1] * 128 + t];
      float x2 = xp[(size_t)s_src[e2 + 2] * 128 + t];
      float x3 = xp[(size_t)s_src[e2 + 3] * 128 + t];
      acc += w0 * x0 + w1 * x1 + w2 * x2 + w3 * x3;
    }
    for (; e2 < cnt; ++e2) {
      acc += s_w[h * 32 + e2] * xp[(size_t)s_src[e2] * 128 + t];
    }
    __syncthreads();
  }
  float v = acc / (s_run + 1e-16f) + bias[t];
  // BN (eval) + ELU
  v = (v - rm[t]) * (g[t] * rsqrtf(rv[t] + BN_EPS)) + be[t];
  v = (v > 0.f) ? v : (expf(v) - 1.f);
  out[(size_t)n * 128 + t] = v;
}

// ---------------- layer 3 projection + alphas: xp3[N,2], asrc3, adst3 ----------------
__global__ __launch_bounds__(256) void xp3_k(const float* __restrict__ h2,
                                             const float* __restrict__ W3,
                                             const float* __restrict__ as3,
                                             const float* __restrict__ ad3,
                                             float* __restrict__ xp3,
                                             float* __restrict__ asrc3,
                                             float* __restrict__ adst3) {
  __shared__ float sW[256];
  int t = threadIdx.x;
  sW[t] = W3[t];
  __syncthreads();
  int n = blockIdx.x * 256 + t;
  if (n < NN) {
    const float4* row = (const float4*)(h2 + (size_t)n * 128);
    float y0 = 0.f, y1 = 0.f;
#pragma unroll
    for (int i = 0; i < 32; ++i) {
      float4 v = row[i];
      y0 += v.x * sW[(i * 4 + 0) * 2] + v.y * sW[(i * 4 + 1) * 2] +
            v.z * sW[(i * 4 + 2) * 2] + v.w * sW[(i * 4 + 3) * 2];
      y1 += v.x * sW[(i * 4 + 0) * 2 + 1] + v.y * sW[(i * 4 + 1) * 2 + 1] +
            v.z * sW[(i * 4 + 2) * 2 + 1] + v.w * sW[(i * 4 + 3) * 2 + 1];
    }
    xp3[n * 2] = y0;
    xp3[n * 2 + 1] = y1;
    asrc3[n] = y0 * as3[0] + y1 * as3[1];
    adst3[n] = y0 * ad3[0] + y1 * ad3[1];
  }
}

// ---------------- layer 3 aggregation: wave per node, 1 head, 2 channels ----------------
__global__ __launch_bounds__(256) void agg2_k(const int* __restrict__ row_ofs,
                                              const int* __restrict__ csr_src,
                                              const int* __restrict__ csr_eid,
                                              const float* __restrict__ xp3,
                                              const float* __restrict__ asrc3,
                                              const float* __restrict__ adst3,
                                              const float* __restrict__ ae3,
                                              const float* __restrict__ alpha_sl,
                                              const float* __restrict__ b3,
                                              float* __restrict__ out) {
  int t = threadIdx.x;
  int w = t >> 6, l = t & 63;
  int n = blockIdx.x * 4 + w;
  if (n >= NN) return;
  int beg = row_ofs[n], end = row_ofs[n + 1];
  float adn = adst3[n];
  float asl = alpha_sl[0];
  float m = -1e30f, s = 0.f, a0 = 0.f, a1 = 0.f;
  for (int idx = beg + l; idx < end; idx += 64) {
    int sj = csr_src[idx];
    int eid = csr_eid[idx];
    float aev = (eid < EE) ? ae3[eid] : asl;
    float a = asrc3[sj] + adn + aev;
    a = (a > 0.f) ? a : NEG_SLOPE * a;
    if (a > m) {
      float f = expf(m - a);
      s *= f; a0 *= f; a1 *= f; m = a;
    }
    float ex = expf(a - m);
    s += ex;
    a0 += ex * xp3[sj * 2];
    a1 += ex * xp3[sj * 2 + 1];
  }
  float M = m;
#pragma unroll
  for (int off = 32; off; off >>= 1) M = fmaxf(M, __shfl_xor(M, off, 64));
  float f = expf(m - M);  // m=-1e30 (idle lane) -> 0
  s *= f; a0 *= f; a1 *= f;
#pragma unroll
  for (int off = 32; off; off >>= 1) {
    s += __shfl_xor(s, off, 64);
    a0 += __shfl_xor(a0, off, 64);
    a1 += __shfl_xor(a1, off, 64);
  }
  if (l == 0) {
    float inv = 1.f / (s + 1e-16f);
    out[n * 2] = a0 * inv + b3[0];
    out[n * 2 + 1] = a1 * inv + b3[1];
  }
}

// ---------------- launcher ----------------
extern "C" void kernel_launch(void* const* d_in, const int* in_sizes, int n_in,
                              void* d_out, int out_size, void* d_ws, size_t ws_size,
                              hipStream_t stream) {
  const float* x   = (const float*)d_in[0];
  const int*   ei  = (const int*)d_in[1];
  const float* ea  = (const float*)d_in[2];
  const float* W1  = (const float*)d_in[3];
  const float* as1 = (const float*)d_in[4];
  const float* ad1 = (const float*)d_in[5];
  const float* We1 = (const float*)d_in[6];
  const float* ae1 = (const float*)d_in[7];
  const float* b1  = (const float*)d_in[8];
  const float* g1  = (const float*)d_in[9];
  const float* be1 = (const float*)d_in[10];
  const float* rm1 = (const float*)d_in[11];
  const float* rv1 = (const float*)d_in[12];
  const float* W2  = (const float*)d_in[13];
  const float* as2 = (const float*)d_in[14];
  const float* ad2 = (const float*)d_in[15];
  const float* We2 = (const float*)d_in[16];
  const float* ae2 = (const float*)d_in[17];
  const float* b2  = (const float*)d_in[18];
  const float* g2  = (const float*)d_in[19];
  const float* be2 = (const float*)d_in[20];
  const float* rm2 = (const float*)d_in[21];
  const float* rv2 = (const float*)d_in[22];
  const float* W3  = (const float*)d_in[23];
  const float* as3 = (const float*)d_in[24];
  const float* ad3 = (const float*)d_in[25];
  const float* We3 = (const float*)d_in[26];
  const float* ae3 = (const float*)d_in[27];
  const float* b3  = (const float*)d_in[28];

  const int* srcA = ei;
  const int* dstA = ei + EE;

  char* p = (char*)d_ws;
  auto alloc = [&](size_t bytes) -> void* {
    void* r = (void*)p;
    p += (bytes + 255) & ~(size_t)255;
    return r;
  };
  float* xp    = (float*)alloc(sizeof(float) * (size_t)NN * 128);
  float* hbuf  = (float*)alloc(sizeof(float) * (size_t)NN * 128);
  float* ae1o  = (float*)alloc(sizeof(float) * (size_t)EE * 4);
  float* ae2o  = (float*)alloc(sizeof(float) * (size_t)EE * 4);
  float* ae3o  = (float*)alloc(sizeof(float) * (size_t)EE);
  float* Mbuf  = (float*)alloc(sizeof(float) * 144);
  float* meanp = (float*)alloc(sizeof(float) * (size_t)EA_BLOCKS * 16);
  float* asl   = (float*)alloc(sizeof(float) * 9);
  float* asrc  = (float*)alloc(sizeof(float) * (size_t)NN * 4);
  float* adst  = (float*)alloc(sizeof(float) * (size_t)NN * 4);
  float* xp3   = (float*)alloc(sizeof(float) * (size_t)NN * 2);
  float* asrc3 = (float*)alloc(sizeof(float) * (size_t)NN);
  float* adst3 = (float*)alloc(sizeof(float) * (size_t)NN);
  int* deg     = (int*)alloc(sizeof(int) * (size_t)NN);
  int* part    = (int*)alloc(sizeof(int) * 256);
  int* row_ofs = (int*)alloc(sizeof(int) * (size_t)(NN + 1));
  int* cursor  = (int*)alloc(sizeof(int) * (size_t)NN);
  int* csr_src = (int*)alloc(sizeof(int) * (size_t)ETOT);
  int* csr_eid = (int*)alloc(sizeof(int) * (size_t)ETOT);

  hipMemsetAsync(deg, 0, NN * sizeof(int), stream);

  compute_M_k<<<1, 64, 0, stream>>>(We1, ae1, We2, ae2, We3, ae3, Mbuf);
  ea_pass_k<<<EA_BLOCKS, 256, 0, stream>>>(ea, Mbuf, ae1o, ae2o, ae3o, meanp);
  selfloop_k<<<1, 256, 0, stream>>>(meanp, Mbuf, asl);
  deg_k<<<(ETOT + 255) / 256, 256, 0, stream>>>(dstA, deg);
  scan_part_k<<<NB_SCAN, 256, 0, stream>>>(deg, part);
  scan_base_k<<<1, 256, 0, stream>>>(part);
  scan_fill_k<<<NB_SCAN, 256, 0, stream>>>(deg, part, row_ofs, cursor);
  fill_k<<<(ETOT + 255) / 256, 256, 0, stream>>>(srcA, dstA, cursor, csr_src, csr_eid);

  // ---- layer 1 ----
  gemm128_k<<<(NN + 63) / 64, 256, 0, stream>>>(x, W1, xp, NN);
  node_alpha_k<<<(NN * 4 + 255) / 256, 256, 0, stream>>>(xp, as1, ad1, asrc, adst);
  agg128_k<<<NN, 128, 0, stream>>>(row_ofs, csr_src, csr_eid, xp, asrc, adst,
                                   ae1o, asl, b1, g1, be1, rm1, rv1, hbuf);
  // ---- layer 2 ----
  gemm128_k<<<(NN + 63) / 64, 256, 0, stream>>>(hbuf, W2, xp, NN);
  node_alpha_k<<<(NN * 4 + 255) / 256, 256, 0, stream>>>(xp, as2, ad2, asrc, adst);
  agg128_k<<<NN, 128, 0, stream>>>(row_ofs, csr_src, csr_eid, xp, asrc, adst,
                                   ae2o, asl + 4, b2, g2, be2, rm2, rv2, hbuf);
  // ---- layer 3 ----
  xp3_k<<<(NN + 255) / 256, 256, 0, stream>>>(hbuf, W3, as3, ad3, xp3, asrc3, adst3);
  agg2_k<<<(NN + 3) / 4, 256, 0, stream>>>(row_ofs, csr_src, csr_eid, xp3, asrc3,
                                           adst3, ae3o, asl + 8, b3, (float*)d_out);
}

// Round 3
// 577.868 us; speedup vs baseline: 1.6536x; 1.1925x over previous
//
#include <hip/hip_runtime.h>
#include <math.h>

#define NN 50000
#define EE 1600000
#define ETOT (EE + NN)
#define NEG_SLOPE 0.2f
#define BN_EPS 1e-5f
#define FILL_BLOCKS 1024
#define NB_SCAN ((NN + 255) / 256)

// Edge record in CSR order, 64B aligned:
// float[0..3]  = ae1 (alpha_e layer1, per head)
// float[4..7]  = ae2
// float[8]     = ae3
// float[9]     = src index (bit-cast int)
// float[10..15]= pad (keeps scatter writes full-line)

// ---------------- M[d,h] = sum_c We[d, h*32+c] * ae[h,c] (per layer) ----------------
__global__ void compute_M_k(const float* __restrict__ We1, const float* __restrict__ ae1,
                            const float* __restrict__ We2, const float* __restrict__ ae2,
                            const float* __restrict__ We3, const float* __restrict__ ae3,
                            float* __restrict__ M) {
  int t = threadIdx.x;
  if (t < 64) {
    int d = t >> 2, h = t & 3;
    float s1 = 0.f, s2 = 0.f;
    for (int c = 0; c < 32; ++c) {
      s1 += We1[d * 128 + h * 32 + c] * ae1[h * 32 + c];
      s2 += We2[d * 128 + h * 32 + c] * ae2[h * 32 + c];
    }
    M[t] = s1;
    M[64 + t] = s2;
  }
  if (t < 16) {
    M[128 + t] = We3[t * 2] * ae3[0] + We3[t * 2 + 1] * ae3[1];
  }
}

// ---------------- CSR build ----------------
__global__ void deg_k(const int* __restrict__ dst, int* __restrict__ deg) {
  int e = blockIdx.x * blockDim.x + threadIdx.x;
  if (e < EE) atomicAdd(&deg[dst[e]], 1);
}

__global__ __launch_bounds__(256) void scan_part_k(const int* __restrict__ deg,
                                                   int* __restrict__ part) {
  int t = threadIdx.x;
  int i = blockIdx.x * 256 + t;
  int v = (i < NN) ? deg[i] + 1 : 0;  // +1 self loop
#pragma unroll
  for (int off = 32; off; off >>= 1) v += __shfl_xor(v, off, 64);
  __shared__ int s[4];
  if ((t & 63) == 0) s[t >> 6] = v;
  __syncthreads();
  if (t == 0) part[blockIdx.x] = s[0] + s[1] + s[2] + s[3];
}

__global__ __launch_bounds__(256) void scan_base_k(int* __restrict__ part) {
  __shared__ int s[256];
  int t = threadIdx.x;
  int v = (t < NB_SCAN) ? part[t] : 0;
  s[t] = v;
  __syncthreads();
  for (int off = 1; off < 256; off <<= 1) {
    int u = (t >= off) ? s[t - off] : 0;
    __syncthreads();
    s[t] += u;
    __syncthreads();
  }
  if (t < NB_SCAN) part[t] = s[t] - v;
}

__global__ __launch_bounds__(256) void scan_fill_k(const int* __restrict__ deg,
                                                   const int* __restrict__ part,
                                                   int* __restrict__ row_ofs,
                                                   int* __restrict__ cursor) {
  __shared__ int s[256];
  int t = threadIdx.x;
  int i = blockIdx.x * 256 + t;
  int v = (i < NN) ? deg[i] + 1 : 0;
  s[t] = v;
  __syncthreads();
  for (int off = 1; off < 256; off <<= 1) {
    int u = (t >= off) ? s[t - off] : 0;
    __syncthreads();
    s[t] += u;
    __syncthreads();
  }
  int excl = s[t] - v + part[blockIdx.x];
  if (i < NN) {
    row_ofs[i] = excl;
    cursor[i] = excl + 1;  // slot excl reserved for the self loop
  }
  if (i == NN - 1) row_ofs[NN] = ETOT;
}

// ---- fill: read ea (coalesced), compute ae1/ae2/ae3, scatter full-line records;
//      also accumulates the edge_attr mean partials (for self-loop fill) ----
__global__ __launch_bounds__(256) void fill_k(const int* __restrict__ src,
                                              const int* __restrict__ dst,
                                              const float* __restrict__ ea,
                                              const float* __restrict__ M,
                                              int* __restrict__ cursor,
                                              float4* __restrict__ recs,
                                              float* __restrict__ mean_part) {
  __shared__ float sM[144];
  int t = threadIdx.x;
  if (t < 144) sM[t] = M[t];
  __syncthreads();
  float macc[16];
#pragma unroll
  for (int d = 0; d < 16; ++d) macc[d] = 0.f;

  for (int e = blockIdx.x * 256 + t; e < EE; e += FILL_BLOCKS * 256) {
    float v[16];
    const float4* p = (const float4*)(ea + (size_t)e * 16);
    float4 q0 = p[0], q1 = p[1], q2 = p[2], q3 = p[3];
    v[0] = q0.x; v[1] = q0.y; v[2] = q0.z; v[3] = q0.w;
    v[4] = q1.x; v[5] = q1.y; v[6] = q1.z; v[7] = q1.w;
    v[8] = q2.x; v[9] = q2.y; v[10] = q2.z; v[11] = q2.w;
    v[12] = q3.x; v[13] = q3.y; v[14] = q3.z; v[15] = q3.w;
    float a1[4], a2[4];
#pragma unroll
    for (int h = 0; h < 4; ++h) {
      float s1 = 0.f, s2 = 0.f;
#pragma unroll
      for (int d = 0; d < 16; ++d) {
        s1 += v[d] * sM[d * 4 + h];
        s2 += v[d] * sM[64 + d * 4 + h];
      }
      a1[h] = s1; a2[h] = s2;
    }
    float a3 = 0.f;
#pragma unroll
    for (int d = 0; d < 16; ++d) a3 += v[d] * sM[128 + d];
#pragma unroll
    for (int d = 0; d < 16; ++d) macc[d] += v[d];

    int dn = dst[e], sn = src[e];
    int pos = atomicAdd(&cursor[dn], 1);
    float4* r = recs + (size_t)pos * 4;
    r[0] = make_float4(a1[0], a1[1], a1[2], a1[3]);
    r[1] = make_float4(a2[0], a2[1], a2[2], a2[3]);
    r[2] = make_float4(a3, __int_as_float(sn), 0.f, 0.f);
    r[3] = make_float4(0.f, 0.f, 0.f, 0.f);
  }
#pragma unroll
  for (int d = 0; d < 16; ++d) {
#pragma unroll
    for (int off = 32; off; off >>= 1) macc[d] += __shfl_xor(macc[d], off, 64);
  }
  __shared__ float swsum[4][16];
  int w = t >> 6, l = t & 63;
  if (l == 0) {
#pragma unroll
    for (int d = 0; d < 16; ++d) swsum[w][d] = macc[d];
  }
  __syncthreads();
  if (t < 16) {
    mean_part[(size_t)blockIdx.x * 16 + t] =
        swsum[0][t] + swsum[1][t] + swsum[2][t] + swsum[3][t];
  }
}

// -------- reduce mean partials -> asl[0..3]=L1, [4..7]=L2, [8]=L3 --------
__global__ __launch_bounds__(256) void selfloop_k(const float* __restrict__ mean_part,
                                                  const float* __restrict__ M,
                                                  float* __restrict__ alpha_sl) {
  __shared__ float s[256];
  int t = threadIdx.x;
  int d = t & 15, c = t >> 4;
  float v = 0.f;
  for (int i = c * 64; i < (c + 1) * 64; ++i) v += mean_part[(size_t)i * 16 + d];
  s[t] = v;
  __syncthreads();
  if (t < 16) {
    float sum = 0.f;
    for (int c2 = 0; c2 < 16; ++c2) sum += s[c2 * 16 + t];
    s[t] = sum / (float)EE;
  }
  __syncthreads();
  if (t < 9) {
    float r = 0.f;
    if (t < 4) {
      for (int dd = 0; dd < 16; ++dd) r += s[dd] * M[dd * 4 + t];
    } else if (t < 8) {
      int h = t - 4;
      for (int dd = 0; dd < 16; ++dd) r += s[dd] * M[64 + dd * 4 + h];
    } else {
      for (int dd = 0; dd < 16; ++dd) r += s[dd] * M[128 + dd];
    }
    alpha_sl[t] = r;
  }
}

// -------- self-loop records at slot row_ofs[n] --------
__global__ __launch_bounds__(256) void slrec_k(const int* __restrict__ row_ofs,
                                               const float* __restrict__ asl,
                                               float4* __restrict__ recs) {
  int n = blockIdx.x * 256 + threadIdx.x;
  if (n < NN) {
    float4 A = make_float4(asl[0], asl[1], asl[2], asl[3]);
    float4 B = make_float4(asl[4], asl[5], asl[6], asl[7]);
    float4 Cc = make_float4(asl[8], __int_as_float(n), 0.f, 0.f);
    float4* r = recs + (size_t)row_ofs[n] * 4;
    r[0] = A; r[1] = B; r[2] = Cc; r[3] = make_float4(0.f, 0.f, 0.f, 0.f);
  }
}

// ---- GEMM 64x64 tiles (2 blocks/CU) + fused alpha_src/alpha_dst epilogue ----
__global__ __launch_bounds__(256) void gemm128a_k(const float* __restrict__ X,
                                                  const float* __restrict__ W,
                                                  const float* __restrict__ as,
                                                  const float* __restrict__ ad,
                                                  float* __restrict__ Y,
                                                  float* __restrict__ asrc,
                                                  float* __restrict__ adst,
                                                  int nrows) {
  __shared__ float sW[128 * 64];
  __shared__ float sX[64 * 132];
  __shared__ float sas[128], sad[128];
  int t = threadIdx.x;
  int r0 = blockIdx.x * 64;
  int cb = blockIdx.y;  // column half: heads 2*cb, 2*cb+1
  if (t < 128) { sas[t] = as[t]; sad[t] = ad[t]; }
#pragma unroll
  for (int i = 0; i < 8; ++i) {
    int flat = t + i * 256;          // float4 index over 128x64 tile
    int k = flat >> 4, c4 = flat & 15;
    *(float4*)&sW[k * 64 + c4 * 4] = *(const float4*)&W[k * 128 + cb * 64 + c4 * 4];
  }
  int rows = nrows - r0; if (rows > 64) rows = 64;
#pragma unroll
  for (int i = 0; i < 8; ++i) {
    int flat = t + i * 256;          // float4 index over 64x128 tile
    int r = flat >> 5, k4 = flat & 31;
    if (r < rows)
      *(float4*)&sX[r * 132 + k4 * 4] = *(const float4*)&X[(size_t)(r0 + r) * 128 + k4 * 4];
  }
  __syncthreads();
  int cq = t & 15, rl = t >> 4;
  float4 acc[4];
#pragma unroll
  for (int i = 0; i < 4; ++i) acc[i] = make_float4(0.f, 0.f, 0.f, 0.f);

  for (int k = 0; k < 128; k += 4) {
    float4 w0 = *(float4*)&sW[(k + 0) * 64 + cq * 4];
    float4 w1 = *(float4*)&sW[(k + 1) * 64 + cq * 4];
    float4 w2 = *(float4*)&sW[(k + 2) * 64 + cq * 4];
    float4 w3 = *(float4*)&sW[(k + 3) * 64 + cq * 4];
#pragma unroll
    for (int i = 0; i < 4; ++i) {
      float4 xv = *(float4*)&sX[(rl + i * 16) * 132 + k];
      acc[i].x += xv.x * w0.x + xv.y * w1.x + xv.z * w2.x + xv.w * w3.x;
      acc[i].y += xv.x * w0.y + xv.y * w1.y + xv.z * w2.y + xv.w * w3.y;
      acc[i].z += xv.x * w0.z + xv.y * w1.z + xv.z * w2.z + xv.w * w3.z;
      acc[i].w += xv.x * w0.w + xv.y * w1.w + xv.z * w2.w + xv.w * w3.w;
    }
  }
  int h = cb * 2 + (cq >> 3);
  int col0 = cb * 64 + cq * 4;
#pragma unroll
  for (int i = 0; i < 4; ++i) {
    int r = rl + i * 16;
    if (r < rows) {
      *(float4*)&Y[(size_t)(r0 + r) * 128 + col0] = acc[i];
      float s1 = acc[i].x * sas[col0] + acc[i].y * sas[col0 + 1] +
                 acc[i].z * sas[col0 + 2] + acc[i].w * sas[col0 + 3];
      float s2 = acc[i].x * sad[col0] + acc[i].y * sad[col0 + 1] +
                 acc[i].z * sad[col0 + 2] + acc[i].w * sad[col0 + 3];
      s1 += __shfl_xor(s1, 1, 8); s1 += __shfl_xor(s1, 2, 8); s1 += __shfl_xor(s1, 4, 8);
      s2 += __shfl_xor(s2, 1, 8); s2 += __shfl_xor(s2, 2, 8); s2 += __shfl_xor(s2, 4, 8);
      if ((cq & 7) == 0) {
        asrc[(size_t)(r0 + r) * 4 + h] = s1;
        adst[(size_t)(r0 + r) * 4 + h] = s2;
      }
    }
  }
}

// ------- per-node aggregation, H=4 C=32, 64-edge chunks, fused bias+BN+ELU -------
__global__ __launch_bounds__(128) void agg128_k(
    const int* __restrict__ row_ofs, const float4* __restrict__ recs,
    const float* __restrict__ xp, const float* __restrict__ asrc,
    const float* __restrict__ adst, int aofs,
    const float* __restrict__ bias, const float* __restrict__ g,
    const float* __restrict__ be, const float* __restrict__ rm,
    const float* __restrict__ rv, float* __restrict__ out) {
  int n = blockIdx.x;
  int t = threadIdx.x;
  int h = t >> 5;   // head group
  int j = t & 31;   // edge slot
  __shared__ float s_w[4 * 64];
  __shared__ int s_src[64];
  int beg = row_ofs[n], end = row_ofs[n + 1];
  float adn = adst[(size_t)n * 4 + h];
  float m_run = -1e30f, s_run = 0.f, acc = 0.f;

  for (int base = beg; base < end; base += 64) {
    int cnt = end - base; if (cnt > 64) cnt = 64;
    float a0 = -1e30f, a1 = -1e30f;
    if (j < cnt) {
      const float* r = (const float*)(recs + (size_t)(base + j) * 4);
      int sj = __float_as_int(r[9]);
      float ae = r[aofs + h];
      if (h == 0) s_src[j] = sj;
      float a = asrc[(size_t)sj * 4 + h] + adn + ae;
      a0 = (a > 0.f) ? a : NEG_SLOPE * a;
    }
    if (j + 32 < cnt) {
      const float* r = (const float*)(recs + (size_t)(base + j + 32) * 4);
      int sj = __float_as_int(r[9]);
      float ae = r[aofs + h];
      if (h == 0) s_src[j + 32] = sj;
      float a = asrc[(size_t)sj * 4 + h] + adn + ae;
      a1 = (a > 0.f) ? a : NEG_SLOPE * a;
    }
    float cm = fmaxf(a0, a1);
#pragma unroll
    for (int off = 16; off; off >>= 1) cm = fmaxf(cm, __shfl_xor(cm, off, 32));
    if (cm > m_run) {
      float f = expf(m_run - cm);
      s_run *= f; acc *= f; m_run = cm;
    }
    float ex0 = (j < cnt) ? expf(a0 - m_run) : 0.f;
    float ex1 = (j + 32 < cnt) ? expf(a1 - m_run) : 0.f;
    s_w[h * 64 + j] = ex0;
    s_w[h * 64 + j + 32] = ex1;
    float se = ex0 + ex1;
#pragma unroll
    for (int off = 16; off; off >>= 1) se += __shfl_xor(se, off, 32);
    s_run += se;
    __syncthreads();
    int e2 = 0;
    for (; e2 + 4 <= cnt; e2 += 4) {
      float w0 = s_w[h * 64 + e2 + 0];
      float w1 = s_w[h * 64 + e2 + 1];
      float w2 = s_w[h * 64 + e2 + 2];
      float w3 = s_w[h * 64 + e2 + 3];
      float x0 = xp[(size_t)s_src[e2 + 0] * 128 + t];
      float x1 = xp[(size_t)s_src[e2 + 1] * 128 + t];
      float x2 = xp[(size_t)s_src[e2 + 2] * 128 + t];
      float x3 = xp[(size_t)s_src[e2 + 3] * 128 + t];
      acc += w0 * x0 + w1 * x1 + w2 * x2 + w3 * x3;
    }
    for (; e2 < cnt; ++e2) {
      acc += s_w[h * 64 + e2] * xp[(size_t)s_src[e2] * 128 + t];
    }
    __syncthreads();
  }
  float v = acc / (s_run + 1e-16f) + bias[t];
  v = (v - rm[t]) * (g[t] * rsqrtf(rv[t] + BN_EPS)) + be[t];
  v = (v > 0.f) ? v : (expf(v) - 1.f);
  out[(size_t)n * 128 + t] = v;
}

// ---------------- layer 3 projection + alphas ----------------
__global__ __launch_bounds__(256) void xp3_k(const float* __restrict__ h2,
                                             const float* __restrict__ W3,
                                             const float* __restrict__ as3,
                                             const float* __restrict__ ad3,
                                             float* __restrict__ xp3,
                                             float* __restrict__ asrc3,
                                             float* __restrict__ adst3) {
  __shared__ float sW[256];
  int t = threadIdx.x;
  sW[t] = W3[t];
  __syncthreads();
  int n = blockIdx.x * 256 + t;
  if (n < NN) {
    const float4* row = (const float4*)(h2 + (size_t)n * 128);
    float y0 = 0.f, y1 = 0.f;
#pragma unroll
    for (int i = 0; i < 32; ++i) {
      float4 v = row[i];
      y0 += v.x * sW[(i * 4 + 0) * 2] + v.y * sW[(i * 4 + 1) * 2] +
            v.z * sW[(i * 4 + 2) * 2] + v.w * sW[(i * 4 + 3) * 2];
      y1 += v.x * sW[(i * 4 + 0) * 2 + 1] + v.y * sW[(i * 4 + 1) * 2 + 1] +
            v.z * sW[(i * 4 + 2) * 2 + 1] + v.w * sW[(i * 4 + 3) * 2 + 1];
    }
    xp3[n * 2] = y0;
    xp3[n * 2 + 1] = y1;
    asrc3[n] = y0 * as3[0] + y1 * as3[1];
    adst3[n] = y0 * ad3[0] + y1 * ad3[1];
  }
}

// ---------------- layer 3 aggregation: wave per node ----------------
__global__ __launch_bounds__(256) void agg2_k(const int* __restrict__ row_ofs,
                                              const float4* __restrict__ recs,
                                              const float* __restrict__ xp3,
                                              const float* __restrict__ asrc3,
                                              const float* __restrict__ adst3,
                                              const float* __restrict__ b3,
                                              float* __restrict__ out) {
  int t = threadIdx.x;
  int w = t >> 6, l = t & 63;
  int n = blockIdx.x * 4 + w;
  if (n >= NN) return;
  int beg = row_ofs[n], end = row_ofs[n + 1];
  float adn = adst3[n];
  float m = -1e30f, s = 0.f, a0 = 0.f, a1 = 0.f;
  for (int idx = beg + l; idx < end; idx += 64) {
    const float* r = (const float*)(recs + (size_t)idx * 4);
    float aev = r[8];
    int sj = __float_as_int(r[9]);
    float a = asrc3[sj] + adn + aev;
    a = (a > 0.f) ? a : NEG_SLOPE * a;
    if (a > m) {
      float f = expf(m - a);
      s *= f; a0 *= f; a1 *= f; m = a;
    }
    float ex = expf(a - m);
    s += ex;
    a0 += ex * xp3[sj * 2];
    a1 += ex * xp3[sj * 2 + 1];
  }
  float M = m;
#pragma unroll
  for (int off = 32; off; off >>= 1) M = fmaxf(M, __shfl_xor(M, off, 64));
  float f = expf(m - M);
  s *= f; a0 *= f; a1 *= f;
#pragma unroll
  for (int off = 32; off; off >>= 1) {
    s += __shfl_xor(s, off, 64);
    a0 += __shfl_xor(a0, off, 64);
    a1 += __shfl_xor(a1, off, 64);
  }
  if (l == 0) {
    float inv = 1.f / (s + 1e-16f);
    out[n * 2] = a0 * inv + b3[0];
    out[n * 2 + 1] = a1 * inv + b3[1];
  }
}

// ---------------- launcher ----------------
extern "C" void kernel_launch(void* const* d_in, const int* in_sizes, int n_in,
                              void* d_out, int out_size, void* d_ws, size_t ws_size,
                              hipStream_t stream) {
  const float* x   = (const float*)d_in[0];
  const int*   ei  = (const int*)d_in[1];
  const float* ea  = (const float*)d_in[2];
  const float* W1  = (const float*)d_in[3];
  const float* as1 = (const float*)d_in[4];
  const float* ad1 = (const float*)d_in[5];
  const float* We1 = (const float*)d_in[6];
  const float* ae1 = (const float*)d_in[7];
  const float* b1  = (const float*)d_in[8];
  const float* g1  = (const float*)d_in[9];
  const float* be1 = (const float*)d_in[10];
  const float* rm1 = (const float*)d_in[11];
  const float* rv1 = (const float*)d_in[12];
  const float* W2  = (const float*)d_in[13];
  const float* as2 = (const float*)d_in[14];
  const float* ad2 = (const float*)d_in[15];
  const float* We2 = (const float*)d_in[16];
  const float* ae2 = (const float*)d_in[17];
  const float* b2  = (const float*)d_in[18];
  const float* g2  = (const float*)d_in[19];
  const float* be2 = (const float*)d_in[20];
  const float* rm2 = (const float*)d_in[21];
  const float* rv2 = (const float*)d_in[22];
  const float* W3  = (const float*)d_in[23];
  const float* as3 = (const float*)d_in[24];
  const float* ad3 = (const float*)d_in[25];
  const float* We3 = (const float*)d_in[26];
  const float* ae3 = (const float*)d_in[27];
  const float* b3  = (const float*)d_in[28];

  const int* srcA = ei;
  const int* dstA = ei + EE;

  char* p = (char*)d_ws;
  auto alloc = [&](size_t bytes) -> void* {
    void* r = (void*)p;
    p += (bytes + 255) & ~(size_t)255;
    return r;
  };
  float4* recs = (float4*)alloc(sizeof(float4) * 4 * (size_t)ETOT);  // 64B/edge
  float* xp    = (float*)alloc(sizeof(float) * (size_t)NN * 128);
  float* hbuf  = (float*)alloc(sizeof(float) * (size_t)NN * 128);
  float* Mbuf  = (float*)alloc(sizeof(float) * 144);
  float* meanp = (float*)alloc(sizeof(float) * (size_t)FILL_BLOCKS * 16);
  float* asl   = (float*)alloc(sizeof(float) * 12);
  float* asrc  = (float*)alloc(sizeof(float) * (size_t)NN * 4);
  float* adst  = (float*)alloc(sizeof(float) * (size_t)NN * 4);
  float* xp3   = (float*)alloc(sizeof(float) * (size_t)NN * 2);
  float* asrc3 = (float*)alloc(sizeof(float) * (size_t)NN);
  float* adst3 = (float*)alloc(sizeof(float) * (size_t)NN);
  int* deg     = (int*)alloc(sizeof(int) * (size_t)NN);
  int* part    = (int*)alloc(sizeof(int) * 256);
  int* row_ofs = (int*)alloc(sizeof(int) * (size_t)(NN + 1));
  int* cursor  = (int*)alloc(sizeof(int) * (size_t)NN);

  hipMemsetAsync(deg, 0, NN * sizeof(int), stream);

  compute_M_k<<<1, 64, 0, stream>>>(We1, ae1, We2, ae2, We3, ae3, Mbuf);
  deg_k<<<(EE + 255) / 256, 256, 0, stream>>>(dstA, deg);
  scan_part_k<<<NB_SCAN, 256, 0, stream>>>(deg, part);
  scan_base_k<<<1, 256, 0, stream>>>(part);
  scan_fill_k<<<NB_SCAN, 256, 0, stream>>>(deg, part, row_ofs, cursor);
  fill_k<<<FILL_BLOCKS, 256, 0, stream>>>(srcA, dstA, ea, Mbuf, cursor, recs, meanp);
  selfloop_k<<<1, 256, 0, stream>>>(meanp, Mbuf, asl);
  slrec_k<<<(NN + 255) / 256, 256, 0, stream>>>(row_ofs, asl, recs);

  // ---- layer 1 ----
  gemm128a_k<<<dim3((NN + 63) / 64, 2), 256, 0, stream>>>(x, W1, as1, ad1, xp, asrc, adst, NN);
  agg128_k<<<NN, 128, 0, stream>>>(row_ofs, recs, xp, asrc, adst, 0,
                                   b1, g1, be1, rm1, rv1, hbuf);
  // ---- layer 2 ----
  gemm128a_k<<<dim3((NN + 63) / 64, 2), 256, 0, stream>>>(hbuf, W2, as2, ad2, xp, asrc, adst, NN);
  agg128_k<<<NN, 128, 0, stream>>>(row_ofs, recs, xp, asrc, adst, 4,
                                   b2, g2, be2, rm2, rv2, hbuf);
  // ---- layer 3 ----
  xp3_k<<<(NN + 255) / 256, 256, 0, stream>>>(hbuf, W3, as3, ad3, xp3, asrc3, adst3);
  agg2_k<<<(NN + 3) / 4, 256, 0, stream>>>(row_ofs, recs, xp3, asrc3, adst3, b3,
                                           (float*)d_out);
}

// Round 4
// 481.806 us; speedup vs baseline: 1.9833x; 1.1994x over previous
//
#include <hip/hip_runtime.h>
#include <hip/hip_fp16.h>
#include <math.h>

#define NN 50000
#define EE 1600000
#define ETOT (EE + NN)
#define NEG_SLOPE 0.2f
#define BN_EPS 1e-5f
#define FILL_BLOCKS 1024
#define NB_SCAN ((NN + 255) / 256)

// Edge record in CSR order, 32B:
// bytes 0..7   : ae1 (layer-1 alpha_e, heads 0..3) as 4x fp16
// bytes 8..15  : ae2 as 4x fp16
// bytes 16..19 : ae3 f32
// bytes 20..23 : src index (int)
// bytes 24..31 : pad

static __device__ inline unsigned pkh2(float a, float b) {
  __half ha = __float2half_rn(a), hb = __float2half_rn(b);
  unsigned short ua = *(unsigned short*)&ha, ub = *(unsigned short*)&hb;
  return ((unsigned)ub << 16) | ua;
}
static __device__ inline float upkh(unsigned u, int hi) {
  unsigned short s = hi ? (unsigned short)(u >> 16) : (unsigned short)(u & 0xffff);
  __half h = *(__half*)&s;
  return __half2float(h);
}

// ---------------- M[d,h] = sum_c We[d, h*32+c] * ae[h,c] (per layer) ----------------
__global__ void compute_M_k(const float* __restrict__ We1, const float* __restrict__ ae1,
                            const float* __restrict__ We2, const float* __restrict__ ae2,
                            const float* __restrict__ We3, const float* __restrict__ ae3,
                            float* __restrict__ M) {
  int t = threadIdx.x;
  if (t < 64) {
    int d = t >> 2, h = t & 3;
    float s1 = 0.f, s2 = 0.f;
    for (int c = 0; c < 32; ++c) {
      s1 += We1[d * 128 + h * 32 + c] * ae1[h * 32 + c];
      s2 += We2[d * 128 + h * 32 + c] * ae2[h * 32 + c];
    }
    M[t] = s1;
    M[64 + t] = s2;
  }
  if (t < 16) {
    M[128 + t] = We3[t * 2] * ae3[0] + We3[t * 2 + 1] * ae3[1];
  }
}

// ---------------- CSR build ----------------
__global__ void deg_k(const int* __restrict__ dst, int* __restrict__ deg) {
  int e = blockIdx.x * blockDim.x + threadIdx.x;
  if (e < EE) atomicAdd(&deg[dst[e]], 1);
}

__global__ __launch_bounds__(256) void scan_part_k(const int* __restrict__ deg,
                                                   int* __restrict__ part) {
  int t = threadIdx.x;
  int i = blockIdx.x * 256 + t;
  int v = (i < NN) ? deg[i] + 1 : 0;  // +1 self loop
#pragma unroll
  for (int off = 32; off; off >>= 1) v += __shfl_xor(v, off, 64);
  __shared__ int s[4];
  if ((t & 63) == 0) s[t >> 6] = v;
  __syncthreads();
  if (t == 0) part[blockIdx.x] = s[0] + s[1] + s[2] + s[3];
}

__global__ __launch_bounds__(256) void scan_base_k(int* __restrict__ part) {
  __shared__ int s[256];
  int t = threadIdx.x;
  int v = (t < NB_SCAN) ? part[t] : 0;
  s[t] = v;
  __syncthreads();
  for (int off = 1; off < 256; off <<= 1) {
    int u = (t >= off) ? s[t - off] : 0;
    __syncthreads();
    s[t] += u;
    __syncthreads();
  }
  if (t < NB_SCAN) part[t] = s[t] - v;
}

__global__ __launch_bounds__(256) void scan_fill_k(const int* __restrict__ deg,
                                                   const int* __restrict__ part,
                                                   int* __restrict__ row_ofs,
                                                   int* __restrict__ cursor) {
  __shared__ int s[256];
  int t = threadIdx.x;
  int i = blockIdx.x * 256 + t;
  int v = (i < NN) ? deg[i] + 1 : 0;
  s[t] = v;
  __syncthreads();
  for (int off = 1; off < 256; off <<= 1) {
    int u = (t >= off) ? s[t - off] : 0;
    __syncthreads();
    s[t] += u;
    __syncthreads();
  }
  int excl = s[t] - v + part[blockIdx.x];
  if (i < NN) {
    row_ofs[i] = excl;
    cursor[i] = excl + 1;  // slot excl reserved for the self loop
  }
  if (i == NN - 1) row_ofs[NN] = ETOT;
}

// ---- fill: read ea (coalesced), compute ae1/ae2/ae3, scatter 32B records;
//      also accumulates the edge_attr mean partials (for self-loop fill) ----
__global__ __launch_bounds__(256) void fill_k(const int* __restrict__ src,
                                              const int* __restrict__ dst,
                                              const float* __restrict__ ea,
                                              const float* __restrict__ M,
                                              int* __restrict__ cursor,
                                              float4* __restrict__ recs,
                                              float* __restrict__ mean_part) {
  __shared__ float sM[144];
  int t = threadIdx.x;
  if (t < 144) sM[t] = M[t];
  __syncthreads();
  float macc[16];
#pragma unroll
  for (int d = 0; d < 16; ++d) macc[d] = 0.f;

  for (int e = blockIdx.x * 256 + t; e < EE; e += FILL_BLOCKS * 256) {
    float v[16];
    const float4* p = (const float4*)(ea + (size_t)e * 16);
    float4 q0 = p[0], q1 = p[1], q2 = p[2], q3 = p[3];
    v[0] = q0.x; v[1] = q0.y; v[2] = q0.z; v[3] = q0.w;
    v[4] = q1.x; v[5] = q1.y; v[6] = q1.z; v[7] = q1.w;
    v[8] = q2.x; v[9] = q2.y; v[10] = q2.z; v[11] = q2.w;
    v[12] = q3.x; v[13] = q3.y; v[14] = q3.z; v[15] = q3.w;
    float a1[4], a2[4];
#pragma unroll
    for (int h = 0; h < 4; ++h) {
      float s1 = 0.f, s2 = 0.f;
#pragma unroll
      for (int d = 0; d < 16; ++d) {
        s1 += v[d] * sM[d * 4 + h];
        s2 += v[d] * sM[64 + d * 4 + h];
      }
      a1[h] = s1; a2[h] = s2;
    }
    float a3 = 0.f;
#pragma unroll
    for (int d = 0; d < 16; ++d) a3 += v[d] * sM[128 + d];
#pragma unroll
    for (int d = 0; d < 16; ++d) macc[d] += v[d];

    int dn = dst[e], sn = src[e];
    int pos = atomicAdd(&cursor[dn], 1);
    float4 r0, r1;
    r0.x = __uint_as_float(pkh2(a1[0], a1[1]));
    r0.y = __uint_as_float(pkh2(a1[2], a1[3]));
    r0.z = __uint_as_float(pkh2(a2[0], a2[1]));
    r0.w = __uint_as_float(pkh2(a2[2], a2[3]));
    r1.x = a3;
    r1.y = __int_as_float(sn);
    r1.z = 0.f; r1.w = 0.f;
    recs[(size_t)pos * 2] = r0;
    recs[(size_t)pos * 2 + 1] = r1;
  }
#pragma unroll
  for (int d = 0; d < 16; ++d) {
#pragma unroll
    for (int off = 32; off; off >>= 1) macc[d] += __shfl_xor(macc[d], off, 64);
  }
  __shared__ float swsum[4][16];
  int w = t >> 6, l = t & 63;
  if (l == 0) {
#pragma unroll
    for (int d = 0; d < 16; ++d) swsum[w][d] = macc[d];
  }
  __syncthreads();
  if (t < 16) {
    mean_part[(size_t)blockIdx.x * 16 + t] =
        swsum[0][t] + swsum[1][t] + swsum[2][t] + swsum[3][t];
  }
}

// -------- reduce mean partials -> asl[0..3]=L1, [4..7]=L2, [8]=L3 --------
__global__ __launch_bounds__(256) void selfloop_k(const float* __restrict__ mean_part,
                                                  const float* __restrict__ M,
                                                  float* __restrict__ alpha_sl) {
  __shared__ float s[256];
  int t = threadIdx.x;
  int d = t & 15, c = t >> 4;
  float v = 0.f;
  for (int i = c * 64; i < (c + 1) * 64; ++i) v += mean_part[(size_t)i * 16 + d];
  s[t] = v;
  __syncthreads();
  if (t < 16) {
    float sum = 0.f;
    for (int c2 = 0; c2 < 16; ++c2) sum += s[c2 * 16 + t];
    s[t] = sum / (float)EE;
  }
  __syncthreads();
  if (t < 9) {
    float r = 0.f;
    if (t < 4) {
      for (int dd = 0; dd < 16; ++dd) r += s[dd] * M[dd * 4 + t];
    } else if (t < 8) {
      int h = t - 4;
      for (int dd = 0; dd < 16; ++dd) r += s[dd] * M[64 + dd * 4 + h];
    } else {
      for (int dd = 0; dd < 16; ++dd) r += s[dd] * M[128 + dd];
    }
    alpha_sl[t] = r;
  }
}

// -------- self-loop records at slot row_ofs[n] --------
__global__ __launch_bounds__(256) void slrec_k(const int* __restrict__ row_ofs,
                                               const float* __restrict__ asl,
                                               float4* __restrict__ recs) {
  int n = blockIdx.x * 256 + threadIdx.x;
  if (n < NN) {
    float4 r0, r1;
    r0.x = __uint_as_float(pkh2(asl[0], asl[1]));
    r0.y = __uint_as_float(pkh2(asl[2], asl[3]));
    r0.z = __uint_as_float(pkh2(asl[4], asl[5]));
    r0.w = __uint_as_float(pkh2(asl[6], asl[7]));
    r1.x = asl[8];
    r1.y = __int_as_float(n);
    r1.z = 0.f; r1.w = 0.f;
    size_t base = (size_t)row_ofs[n] * 2;
    recs[base] = r0;
    recs[base + 1] = r1;
  }
}

// ---- GEMM 64x64 tiles + fused alpha epilogue; Y written as fp16 ----
__global__ __launch_bounds__(256) void gemm128a_k(const float* __restrict__ X,
                                                  const float* __restrict__ W,
                                                  const float* __restrict__ as,
                                                  const float* __restrict__ ad,
                                                  __half* __restrict__ Y,
                                                  float* __restrict__ asrc,
                                                  float* __restrict__ adst,
                                                  int nrows) {
  __shared__ float sW[128 * 64];
  __shared__ float sX[64 * 132];
  __shared__ float sas[128], sad[128];
  int t = threadIdx.x;
  int r0 = blockIdx.x * 64;
  int cb = blockIdx.y;  // column half: heads 2*cb, 2*cb+1
  if (t < 128) { sas[t] = as[t]; sad[t] = ad[t]; }
#pragma unroll
  for (int i = 0; i < 8; ++i) {
    int flat = t + i * 256;          // float4 index over 128x64 tile
    int k = flat >> 4, c4 = flat & 15;
    *(float4*)&sW[k * 64 + c4 * 4] = *(const float4*)&W[k * 128 + cb * 64 + c4 * 4];
  }
  int rows = nrows - r0; if (rows > 64) rows = 64;
#pragma unroll
  for (int i = 0; i < 8; ++i) {
    int flat = t + i * 256;          // float4 index over 64x128 tile
    int r = flat >> 5, k4 = flat & 31;
    if (r < rows)
      *(float4*)&sX[r * 132 + k4 * 4] = *(const float4*)&X[(size_t)(r0 + r) * 128 + k4 * 4];
  }
  __syncthreads();
  int cq = t & 15, rl = t >> 4;
  float4 acc[4];
#pragma unroll
  for (int i = 0; i < 4; ++i) acc[i] = make_float4(0.f, 0.f, 0.f, 0.f);

  for (int k = 0; k < 128; k += 4) {
    float4 w0 = *(float4*)&sW[(k + 0) * 64 + cq * 4];
    float4 w1 = *(float4*)&sW[(k + 1) * 64 + cq * 4];
    float4 w2 = *(float4*)&sW[(k + 2) * 64 + cq * 4];
    float4 w3 = *(float4*)&sW[(k + 3) * 64 + cq * 4];
#pragma unroll
    for (int i = 0; i < 4; ++i) {
      float4 xv = *(float4*)&sX[(rl + i * 16) * 132 + k];
      acc[i].x += xv.x * w0.x + xv.y * w1.x + xv.z * w2.x + xv.w * w3.x;
      acc[i].y += xv.x * w0.y + xv.y * w1.y + xv.z * w2.y + xv.w * w3.y;
      acc[i].z += xv.x * w0.z + xv.y * w1.z + xv.z * w2.z + xv.w * w3.z;
      acc[i].w += xv.x * w0.w + xv.y * w1.w + xv.z * w2.w + xv.w * w3.w;
    }
  }
  int h = cb * 2 + (cq >> 3);
  int col0 = cb * 64 + cq * 4;
#pragma unroll
  for (int i = 0; i < 4; ++i) {
    int r = rl + i * 16;
    if (r < rows) {
      uint2 st;
      st.x = pkh2(acc[i].x, acc[i].y);
      st.y = pkh2(acc[i].z, acc[i].w);
      *(uint2*)&Y[(size_t)(r0 + r) * 128 + col0] = st;
      float s1 = acc[i].x * sas[col0] + acc[i].y * sas[col0 + 1] +
                 acc[i].z * sas[col0 + 2] + acc[i].w * sas[col0 + 3];
      float s2 = acc[i].x * sad[col0] + acc[i].y * sad[col0 + 1] +
                 acc[i].z * sad[col0 + 2] + acc[i].w * sad[col0 + 3];
      s1 += __shfl_xor(s1, 1, 8); s1 += __shfl_xor(s1, 2, 8); s1 += __shfl_xor(s1, 4, 8);
      s2 += __shfl_xor(s2, 1, 8); s2 += __shfl_xor(s2, 2, 8); s2 += __shfl_xor(s2, 4, 8);
      if ((cq & 7) == 0) {
        asrc[(size_t)(r0 + r) * 4 + h] = s1;
        adst[(size_t)(r0 + r) * 4 + h] = s2;
      }
    }
  }
}

// ------- per-node aggregation, H=4 C=32, 64-edge chunks, fused bias+BN+ELU -------
__global__ __launch_bounds__(128) void agg128_k(
    const int* __restrict__ row_ofs, const float4* __restrict__ recs,
    const __half* __restrict__ xp, const float* __restrict__ asrc,
    const float* __restrict__ adst, int aofs,
    const float* __restrict__ bias, const float* __restrict__ g,
    const float* __restrict__ be, const float* __restrict__ rm,
    const float* __restrict__ rv, float* __restrict__ out) {
  int n = blockIdx.x;
  int t = threadIdx.x;
  int h = t >> 5;   // head group
  int j = t & 31;   // edge slot
  __shared__ float s_w[4 * 64];
  __shared__ int s_src[64];
  int beg = row_ofs[n], end = row_ofs[n + 1];
  float adn = adst[(size_t)n * 4 + h];
  float m_run = -1e30f, s_run = 0.f, acc = 0.f;

  for (int base = beg; base < end; base += 64) {
    int cnt = end - base; if (cnt > 64) cnt = 64;
    float a0 = -1e30f, a1 = -1e30f;
    if (j < cnt) {
      const char* rp = (const char*)recs + (size_t)(base + j) * 32;
      unsigned w = *(const unsigned*)(rp + aofs * 8 + (h >> 1) * 4);
      float ae = upkh(w, h & 1);
      float2 q1 = *(const float2*)(rp + 16);
      int sj = __float_as_int(q1.y);
      if (h == 0) s_src[j] = sj;
      float a = asrc[(size_t)sj * 4 + h] + adn + ae;
      a0 = (a > 0.f) ? a : NEG_SLOPE * a;
    }
    if (j + 32 < cnt) {
      const char* rp = (const char*)recs + (size_t)(base + j + 32) * 32;
      unsigned w = *(const unsigned*)(rp + aofs * 8 + (h >> 1) * 4);
      float ae = upkh(w, h & 1);
      float2 q1 = *(const float2*)(rp + 16);
      int sj = __float_as_int(q1.y);
      if (h == 0) s_src[j + 32] = sj;
      float a = asrc[(size_t)sj * 4 + h] + adn + ae;
      a1 = (a > 0.f) ? a : NEG_SLOPE * a;
    }
    float cm = fmaxf(a0, a1);
#pragma unroll
    for (int off = 16; off; off >>= 1) cm = fmaxf(cm, __shfl_xor(cm, off, 32));
    if (cm > m_run) {
      float f = expf(m_run - cm);
      s_run *= f; acc *= f; m_run = cm;
    }
    float ex0 = (j < cnt) ? expf(a0 - m_run) : 0.f;
    float ex1 = (j + 32 < cnt) ? expf(a1 - m_run) : 0.f;
    s_w[h * 64 + j] = ex0;
    s_w[h * 64 + j + 32] = ex1;
    float se = ex0 + ex1;
#pragma unroll
    for (int off = 16; off; off >>= 1) se += __shfl_xor(se, off, 32);
    s_run += se;
    __syncthreads();
    int e2 = 0;
    for (; e2 + 4 <= cnt; e2 += 4) {
      float w0 = s_w[h * 64 + e2 + 0];
      float w1 = s_w[h * 64 + e2 + 1];
      float w2 = s_w[h * 64 + e2 + 2];
      float w3 = s_w[h * 64 + e2 + 3];
      float x0 = __half2float(xp[(size_t)s_src[e2 + 0] * 128 + t]);
      float x1 = __half2float(xp[(size_t)s_src[e2 + 1] * 128 + t]);
      float x2 = __half2float(xp[(size_t)s_src[e2 + 2] * 128 + t]);
      float x3 = __half2float(xp[(size_t)s_src[e2 + 3] * 128 + t]);
      acc += w0 * x0 + w1 * x1 + w2 * x2 + w3 * x3;
    }
    for (; e2 < cnt; ++e2) {
      acc += s_w[h * 64 + e2] * __half2float(xp[(size_t)s_src[e2] * 128 + t]);
    }
    __syncthreads();
  }
  float v = acc / (s_run + 1e-16f) + bias[t];
  v = (v - rm[t]) * (g[t] * rsqrtf(rv[t] + BN_EPS)) + be[t];
  v = (v > 0.f) ? v : (expf(v) - 1.f);
  out[(size_t)n * 128 + t] = v;
}

// ---------------- layer 3 projection + alphas ----------------
__global__ __launch_bounds__(256) void xp3_k(const float* __restrict__ h2,
                                             const float* __restrict__ W3,
                                             const float* __restrict__ as3,
                                             const float* __restrict__ ad3,
                                             float* __restrict__ xp3,
                                             float* __restrict__ asrc3,
                                             float* __restrict__ adst3) {
  __shared__ float sW[256];
  int t = threadIdx.x;
  sW[t] = W3[t];
  __syncthreads();
  int n = blockIdx.x * 256 + t;
  if (n < NN) {
    const float4* row = (const float4*)(h2 + (size_t)n * 128);
    float y0 = 0.f, y1 = 0.f;
#pragma unroll
    for (int i = 0; i < 32; ++i) {
      float4 v = row[i];
      y0 += v.x * sW[(i * 4 + 0) * 2] + v.y * sW[(i * 4 + 1) * 2] +
            v.z * sW[(i * 4 + 2) * 2] + v.w * sW[(i * 4 + 3) * 2];
      y1 += v.x * sW[(i * 4 + 0) * 2 + 1] + v.y * sW[(i * 4 + 1) * 2 + 1] +
            v.z * sW[(i * 4 + 2) * 2 + 1] + v.w * sW[(i * 4 + 3) * 2 + 1];
    }
    xp3[n * 2] = y0;
    xp3[n * 2 + 1] = y1;
    asrc3[n] = y0 * as3[0] + y1 * as3[1];
    adst3[n] = y0 * ad3[0] + y1 * ad3[1];
  }
}

// ---------------- layer 3 aggregation: wave per node ----------------
__global__ __launch_bounds__(256) void agg2_k(const int* __restrict__ row_ofs,
                                              const float4* __restrict__ recs,
                                              const float* __restrict__ xp3,
                                              const float* __restrict__ asrc3,
                                              const float* __restrict__ adst3,
                                              const float* __restrict__ b3,
                                              float* __restrict__ out) {
  int t = threadIdx.x;
  int w = t >> 6, l = t & 63;
  int n = blockIdx.x * 4 + w;
  if (n >= NN) return;
  int beg = row_ofs[n], end = row_ofs[n + 1];
  float adn = adst3[n];
  float m = -1e30f, s = 0.f, a0 = 0.f, a1 = 0.f;
  for (int idx = beg + l; idx < end; idx += 64) {
    float2 q1 = *(const float2*)((const char*)recs + (size_t)idx * 32 + 16);
    float aev = q1.x;
    int sj = __float_as_int(q1.y);
    float a = asrc3[sj] + adn + aev;
    a = (a > 0.f) ? a : NEG_SLOPE * a;
    if (a > m) {
      float f = expf(m - a);
      s *= f; a0 *= f; a1 *= f; m = a;
    }
    float ex = expf(a - m);
    s += ex;
    a0 += ex * xp3[sj * 2];
    a1 += ex * xp3[sj * 2 + 1];
  }
  float M = m;
#pragma unroll
  for (int off = 32; off; off >>= 1) M = fmaxf(M, __shfl_xor(M, off, 64));
  float f = expf(m - M);
  s *= f; a0 *= f; a1 *= f;
#pragma unroll
  for (int off = 32; off; off >>= 1) {
    s += __shfl_xor(s, off, 64);
    a0 += __shfl_xor(a0, off, 64);
    a1 += __shfl_xor(a1, off, 64);
  }
  if (l == 0) {
    float inv = 1.f / (s + 1e-16f);
    out[n * 2] = a0 * inv + b3[0];
    out[n * 2 + 1] = a1 * inv + b3[1];
  }
}

// ---------------- launcher ----------------
extern "C" void kernel_launch(void* const* d_in, const int* in_sizes, int n_in,
                              void* d_out, int out_size, void* d_ws, size_t ws_size,
                              hipStream_t stream) {
  const float* x   = (const float*)d_in[0];
  const int*   ei  = (const int*)d_in[1];
  const float* ea  = (const float*)d_in[2];
  const float* W1  = (const float*)d_in[3];
  const float* as1 = (const float*)d_in[4];
  const float* ad1 = (const float*)d_in[5];
  const float* We1 = (const float*)d_in[6];
  const float* ae1 = (const float*)d_in[7];
  const float* b1  = (const float*)d_in[8];
  const float* g1  = (const float*)d_in[9];
  const float* be1 = (const float*)d_in[10];
  const float* rm1 = (const float*)d_in[11];
  const float* rv1 = (const float*)d_in[12];
  const float* W2  = (const float*)d_in[13];
  const float* as2 = (const float*)d_in[14];
  const float* ad2 = (const float*)d_in[15];
  const float* We2 = (const float*)d_in[16];
  const float* ae2 = (const float*)d_in[17];
  const float* b2  = (const float*)d_in[18];
  const float* g2  = (const float*)d_in[19];
  const float* be2 = (const float*)d_in[20];
  const float* rm2 = (const float*)d_in[21];
  const float* rv2 = (const float*)d_in[22];
  const float* W3  = (const float*)d_in[23];
  const float* as3 = (const float*)d_in[24];
  const float* ad3 = (const float*)d_in[25];
  const float* We3 = (const float*)d_in[26];
  const float* ae3 = (const float*)d_in[27];
  const float* b3  = (const float*)d_in[28];

  const int* srcA = ei;
  const int* dstA = ei + EE;

  char* p = (char*)d_ws;
  auto alloc = [&](size_t bytes) -> void* {
    void* r = (void*)p;
    p += (bytes + 255) & ~(size_t)255;
    return r;
  };
  float4* recs = (float4*)alloc(32 * (size_t)ETOT);  // 32B/edge
  __half* xp   = (__half*)alloc(sizeof(__half) * (size_t)NN * 128);
  float* hbuf  = (float*)alloc(sizeof(float) * (size_t)NN * 128);
  float* Mbuf  = (float*)alloc(sizeof(float) * 144);
  float* meanp = (float*)alloc(sizeof(float) * (size_t)FILL_BLOCKS * 16);
  float* asl   = (float*)alloc(sizeof(float) * 12);
  float* asrc  = (float*)alloc(sizeof(float) * (size_t)NN * 4);
  float* adst  = (float*)alloc(sizeof(float) * (size_t)NN * 4);
  float* xp3   = (float*)alloc(sizeof(float) * (size_t)NN * 2);
  float* asrc3 = (float*)alloc(sizeof(float) * (size_t)NN);
  float* adst3 = (float*)alloc(sizeof(float) * (size_t)NN);
  int* deg     = (int*)alloc(sizeof(int) * (size_t)NN);
  int* part    = (int*)alloc(sizeof(int) * 256);
  int* row_ofs = (int*)alloc(sizeof(int) * (size_t)(NN + 1));
  int* cursor  = (int*)alloc(sizeof(int) * (size_t)NN);

  hipMemsetAsync(deg, 0, NN * sizeof(int), stream);

  compute_M_k<<<1, 64, 0, stream>>>(We1, ae1, We2, ae2, We3, ae3, Mbuf);
  deg_k<<<(EE + 255) / 256, 256, 0, stream>>>(dstA, deg);
  scan_part_k<<<NB_SCAN, 256, 0, stream>>>(deg, part);
  scan_base_k<<<1, 256, 0, stream>>>(part);
  scan_fill_k<<<NB_SCAN, 256, 0, stream>>>(deg, part, row_ofs, cursor);
  fill_k<<<FILL_BLOCKS, 256, 0, stream>>>(srcA, dstA, ea, Mbuf, cursor, recs, meanp);
  selfloop_k<<<1, 256, 0, stream>>>(meanp, Mbuf, asl);
  slrec_k<<<(NN + 255) / 256, 256, 0, stream>>>(row_ofs, asl, recs);

  // ---- layer 1 ----
  gemm128a_k<<<dim3((NN + 63) / 64, 2), 256, 0, stream>>>(x, W1, as1, ad1, xp, asrc, adst, NN);
  agg128_k<<<NN, 128, 0, stream>>>(row_ofs, recs, xp, asrc, adst, 0,
                                   b1, g1, be1, rm1, rv1, hbuf);
  // ---- layer 2 ----
  gemm128a_k<<<dim3((NN + 63) / 64, 2), 256, 0, stream>>>(hbuf, W2, as2, ad2, xp, asrc, adst, NN);
  agg128_k<<<NN, 128, 0, stream>>>(row_ofs, recs, xp, asrc, adst, 1,
                                   b2, g2, be2, rm2, rv2, hbuf);
  // ---- layer 3 ----
  xp3_k<<<(NN + 255) / 256, 256, 0, stream>>>(hbuf, W3, as3, ad3, xp3, asrc3, adst3);
  agg2_k<<<(NN + 3) / 4, 256, 0, stream>>>(row_ofs, recs, xp3, asrc3, adst3, b3,
                                           (float*)d_out);
}

// Round 5
// 453.875 us; speedup vs baseline: 2.1053x; 1.0615x over previous
//
#include <hip/hip_runtime.h>
#include <hip/hip_fp16.h>
#include <math.h>

#define NN 50000
#define EE 1600000
#define ETOT (EE + NN)
#define NEG_SLOPE 0.2f
#define BN_EPS 1e-5f
#define FILL_BLOCKS 1024
#define NB_SCAN ((NN + 255) / 256)

// Split edge-record arrays, all in CSR order:
//   recAE1[e] : uint2 = heads 0..3 of layer-1 alpha_e as 4x fp16
//   recAE2[e] : uint2 = heads 0..3 of layer-2 alpha_e
//   rec3[e]   : float = layer-3 alpha_e
//   recSrc[e] : int   = src node index

static __device__ inline unsigned pkh2(float a, float b) {
  __half ha = __float2half_rn(a), hb = __float2half_rn(b);
  unsigned short ua = *(unsigned short*)&ha, ub = *(unsigned short*)&hb;
  return ((unsigned)ub << 16) | ua;
}
static __device__ inline float upkh(unsigned u, int hi) {
  unsigned short s = hi ? (unsigned short)(u >> 16) : (unsigned short)(u & 0xffff);
  __half h = *(__half*)&s;
  return __half2float(h);
}

// ---------------- M[d,h] = sum_c We[d, h*32+c] * ae[h,c] (per layer) ----------------
__global__ void compute_M_k(const float* __restrict__ We1, const float* __restrict__ ae1,
                            const float* __restrict__ We2, const float* __restrict__ ae2,
                            const float* __restrict__ We3, const float* __restrict__ ae3,
                            float* __restrict__ M) {
  int t = threadIdx.x;
  if (t < 64) {
    int d = t >> 2, h = t & 3;
    float s1 = 0.f, s2 = 0.f;
    for (int c = 0; c < 32; ++c) {
      s1 += We1[d * 128 + h * 32 + c] * ae1[h * 32 + c];
      s2 += We2[d * 128 + h * 32 + c] * ae2[h * 32 + c];
    }
    M[t] = s1;
    M[64 + t] = s2;
  }
  if (t < 16) {
    M[128 + t] = We3[t * 2] * ae3[0] + We3[t * 2 + 1] * ae3[1];
  }
}

// ---------------- CSR build ----------------
__global__ void deg_k(const int* __restrict__ dst, int* __restrict__ deg) {
  int e = blockIdx.x * blockDim.x + threadIdx.x;
  if (e < EE) atomicAdd(&deg[dst[e]], 1);
}

__global__ __launch_bounds__(256) void scan_part_k(const int* __restrict__ deg,
                                                   int* __restrict__ part) {
  int t = threadIdx.x;
  int i = blockIdx.x * 256 + t;
  int v = (i < NN) ? deg[i] + 1 : 0;  // +1 self loop
#pragma unroll
  for (int off = 32; off; off >>= 1) v += __shfl_xor(v, off, 64);
  __shared__ int s[4];
  if ((t & 63) == 0) s[t >> 6] = v;
  __syncthreads();
  if (t == 0) part[blockIdx.x] = s[0] + s[1] + s[2] + s[3];
}

__global__ __launch_bounds__(256) void scan_base_k(int* __restrict__ part) {
  __shared__ int s[256];
  int t = threadIdx.x;
  int v = (t < NB_SCAN) ? part[t] : 0;
  s[t] = v;
  __syncthreads();
  for (int off = 1; off < 256; off <<= 1) {
    int u = (t >= off) ? s[t - off] : 0;
    __syncthreads();
    s[t] += u;
    __syncthreads();
  }
  if (t < NB_SCAN) part[t] = s[t] - v;
}

__global__ __launch_bounds__(256) void scan_fill_k(const int* __restrict__ deg,
                                                   const int* __restrict__ part,
                                                   int* __restrict__ row_ofs,
                                                   int* __restrict__ cursor) {
  __shared__ int s[256];
  int t = threadIdx.x;
  int i = blockIdx.x * 256 + t;
  int v = (i < NN) ? deg[i] + 1 : 0;
  s[t] = v;
  __syncthreads();
  for (int off = 1; off < 256; off <<= 1) {
    int u = (t >= off) ? s[t - off] : 0;
    __syncthreads();
    s[t] += u;
    __syncthreads();
  }
  int excl = s[t] - v + part[blockIdx.x];
  if (i < NN) {
    row_ofs[i] = excl;
    cursor[i] = excl + 1;  // slot excl reserved for the self loop
  }
  if (i == NN - 1) row_ofs[NN] = ETOT;
}

// ---- fill: read ea (coalesced), compute alpha_e for all layers, scatter split records;
//      also accumulates the edge_attr mean partials (for self-loop fill) ----
__global__ __launch_bounds__(256) void fill_k(const int* __restrict__ src,
                                              const int* __restrict__ dst,
                                              const float* __restrict__ ea,
                                              const float* __restrict__ M,
                                              int* __restrict__ cursor,
                                              uint2* __restrict__ recAE1,
                                              uint2* __restrict__ recAE2,
                                              float* __restrict__ rec3,
                                              int* __restrict__ recSrc,
                                              float* __restrict__ mean_part) {
  __shared__ float sM[144];
  int t = threadIdx.x;
  if (t < 144) sM[t] = M[t];
  __syncthreads();
  float macc[16];
#pragma unroll
  for (int d = 0; d < 16; ++d) macc[d] = 0.f;

  for (int e = blockIdx.x * 256 + t; e < EE; e += FILL_BLOCKS * 256) {
    float v[16];
    const float4* p = (const float4*)(ea + (size_t)e * 16);
    float4 q0 = p[0], q1 = p[1], q2 = p[2], q3 = p[3];
    v[0] = q0.x; v[1] = q0.y; v[2] = q0.z; v[3] = q0.w;
    v[4] = q1.x; v[5] = q1.y; v[6] = q1.z; v[7] = q1.w;
    v[8] = q2.x; v[9] = q2.y; v[10] = q2.z; v[11] = q2.w;
    v[12] = q3.x; v[13] = q3.y; v[14] = q3.z; v[15] = q3.w;
    float a1[4], a2[4];
#pragma unroll
    for (int h = 0; h < 4; ++h) {
      float s1 = 0.f, s2 = 0.f;
#pragma unroll
      for (int d = 0; d < 16; ++d) {
        s1 += v[d] * sM[d * 4 + h];
        s2 += v[d] * sM[64 + d * 4 + h];
      }
      a1[h] = s1; a2[h] = s2;
    }
    float a3 = 0.f;
#pragma unroll
    for (int d = 0; d < 16; ++d) a3 += v[d] * sM[128 + d];
#pragma unroll
    for (int d = 0; d < 16; ++d) macc[d] += v[d];

    int dn = dst[e], sn = src[e];
    int pos = atomicAdd(&cursor[dn], 1);
    recAE1[pos] = make_uint2(pkh2(a1[0], a1[1]), pkh2(a1[2], a1[3]));
    recAE2[pos] = make_uint2(pkh2(a2[0], a2[1]), pkh2(a2[2], a2[3]));
    rec3[pos] = a3;
    recSrc[pos] = sn;
  }
#pragma unroll
  for (int d = 0; d < 16; ++d) {
#pragma unroll
    for (int off = 32; off; off >>= 1) macc[d] += __shfl_xor(macc[d], off, 64);
  }
  __shared__ float swsum[4][16];
  int w = t >> 6, l = t & 63;
  if (l == 0) {
#pragma unroll
    for (int d = 0; d < 16; ++d) swsum[w][d] = macc[d];
  }
  __syncthreads();
  if (t < 16) {
    mean_part[(size_t)blockIdx.x * 16 + t] =
        swsum[0][t] + swsum[1][t] + swsum[2][t] + swsum[3][t];
  }
}

// -------- reduce mean partials -> asl[0..3]=L1, [4..7]=L2, [8]=L3 --------
__global__ __launch_bounds__(256) void selfloop_k(const float* __restrict__ mean_part,
                                                  const float* __restrict__ M,
                                                  float* __restrict__ alpha_sl) {
  __shared__ float s[256];
  int t = threadIdx.x;
  int d = t & 15, c = t >> 4;
  float v = 0.f;
  for (int i = c * 64; i < (c + 1) * 64; ++i) v += mean_part[(size_t)i * 16 + d];
  s[t] = v;
  __syncthreads();
  if (t < 16) {
    float sum = 0.f;
    for (int c2 = 0; c2 < 16; ++c2) sum += s[c2 * 16 + t];
    s[t] = sum / (float)EE;
  }
  __syncthreads();
  if (t < 9) {
    float r = 0.f;
    if (t < 4) {
      for (int dd = 0; dd < 16; ++dd) r += s[dd] * M[dd * 4 + t];
    } else if (t < 8) {
      int h = t - 4;
      for (int dd = 0; dd < 16; ++dd) r += s[dd] * M[64 + dd * 4 + h];
    } else {
      for (int dd = 0; dd < 16; ++dd) r += s[dd] * M[128 + dd];
    }
    alpha_sl[t] = r;
  }
}

// -------- self-loop records at slot row_ofs[n] --------
__global__ __launch_bounds__(256) void slrec_k(const int* __restrict__ row_ofs,
                                               const float* __restrict__ asl,
                                               uint2* __restrict__ recAE1,
                                               uint2* __restrict__ recAE2,
                                               float* __restrict__ rec3,
                                               int* __restrict__ recSrc) {
  int n = blockIdx.x * 256 + threadIdx.x;
  if (n < NN) {
    int pos = row_ofs[n];
    recAE1[pos] = make_uint2(pkh2(asl[0], asl[1]), pkh2(asl[2], asl[3]));
    recAE2[pos] = make_uint2(pkh2(asl[4], asl[5]), pkh2(asl[6], asl[7]));
    rec3[pos] = asl[8];
    recSrc[pos] = n;
  }
}

// ---- GEMM 64x64 tiles + fused alpha epilogue; Y written as fp16 ----
__global__ __launch_bounds__(256) void gemm128a_k(const float* __restrict__ X,
                                                  const float* __restrict__ W,
                                                  const float* __restrict__ as,
                                                  const float* __restrict__ ad,
                                                  __half* __restrict__ Y,
                                                  float* __restrict__ asrc,
                                                  float* __restrict__ adst,
                                                  int nrows) {
  __shared__ float sW[128 * 64];
  __shared__ float sX[64 * 132];
  __shared__ float sas[128], sad[128];
  int t = threadIdx.x;
  int r0 = blockIdx.x * 64;
  int cb = blockIdx.y;  // column half: heads 2*cb, 2*cb+1
  if (t < 128) { sas[t] = as[t]; sad[t] = ad[t]; }
#pragma unroll
  for (int i = 0; i < 8; ++i) {
    int flat = t + i * 256;          // float4 index over 128x64 tile
    int k = flat >> 4, c4 = flat & 15;
    *(float4*)&sW[k * 64 + c4 * 4] = *(const float4*)&W[k * 128 + cb * 64 + c4 * 4];
  }
  int rows = nrows - r0; if (rows > 64) rows = 64;
#pragma unroll
  for (int i = 0; i < 8; ++i) {
    int flat = t + i * 256;          // float4 index over 64x128 tile
    int r = flat >> 5, k4 = flat & 31;
    if (r < rows)
      *(float4*)&sX[r * 132 + k4 * 4] = *(const float4*)&X[(size_t)(r0 + r) * 128 + k4 * 4];
  }
  __syncthreads();
  int cq = t & 15, rl = t >> 4;
  float4 acc[4];
#pragma unroll
  for (int i = 0; i < 4; ++i) acc[i] = make_float4(0.f, 0.f, 0.f, 0.f);

  for (int k = 0; k < 128; k += 4) {
    float4 w0 = *(float4*)&sW[(k + 0) * 64 + cq * 4];
    float4 w1 = *(float4*)&sW[(k + 1) * 64 + cq * 4];
    float4 w2 = *(float4*)&sW[(k + 2) * 64 + cq * 4];
    float4 w3 = *(float4*)&sW[(k + 3) * 64 + cq * 4];
#pragma unroll
    for (int i = 0; i < 4; ++i) {
      float4 xv = *(float4*)&sX[(rl + i * 16) * 132 + k];
      acc[i].x += xv.x * w0.x + xv.y * w1.x + xv.z * w2.x + xv.w * w3.x;
      acc[i].y += xv.x * w0.y + xv.y * w1.y + xv.z * w2.y + xv.w * w3.y;
      acc[i].z += xv.x * w0.z + xv.y * w1.z + xv.z * w2.z + xv.w * w3.z;
      acc[i].w += xv.x * w0.w + xv.y * w1.w + xv.z * w2.w + xv.w * w3.w;
    }
  }
  int h = cb * 2 + (cq >> 3);
  int col0 = cb * 64 + cq * 4;
#pragma unroll
  for (int i = 0; i < 4; ++i) {
    int r = rl + i * 16;
    if (r < rows) {
      uint2 st;
      st.x = pkh2(acc[i].x, acc[i].y);
      st.y = pkh2(acc[i].z, acc[i].w);
      *(uint2*)&Y[(size_t)(r0 + r) * 128 + col0] = st;
      float s1 = acc[i].x * sas[col0] + acc[i].y * sas[col0 + 1] +
                 acc[i].z * sas[col0 + 2] + acc[i].w * sas[col0 + 3];
      float s2 = acc[i].x * sad[col0] + acc[i].y * sad[col0 + 1] +
                 acc[i].z * sad[col0 + 2] + acc[i].w * sad[col0 + 3];
      s1 += __shfl_xor(s1, 1, 8); s1 += __shfl_xor(s1, 2, 8); s1 += __shfl_xor(s1, 4, 8);
      s2 += __shfl_xor(s2, 1, 8); s2 += __shfl_xor(s2, 2, 8); s2 += __shfl_xor(s2, 4, 8);
      if ((cq & 7) == 0) {
        asrc[(size_t)(r0 + r) * 4 + h] = s1;
        adst[(size_t)(r0 + r) * 4 + h] = s2;
      }
    }
  }
}

// ------- per-node aggregation, H=4 C=32, 64-edge chunks, fused bias+BN+ELU -------
// alpha role: h = t>>5 (head), j = t&31 (edge slot)
// accum role: e4 = t>>4 (8 edge sub-slots), gg = t&15 (16 channel groups of 8 fp16)
__global__ __launch_bounds__(128) void agg128_k(
    const int* __restrict__ row_ofs, const unsigned* __restrict__ recAE,
    const int* __restrict__ recSrc, const __half* __restrict__ xp,
    const float* __restrict__ asrc, const float* __restrict__ adst,
    const float* __restrict__ bias, const float* __restrict__ g,
    const float* __restrict__ be, const float* __restrict__ rm,
    const float* __restrict__ rv, float* __restrict__ out) {
  int n = blockIdx.x;
  int t = threadIdx.x;
  int h = t >> 5, j = t & 31;
  int e4 = t >> 4, gg = t & 15;
  int hh = gg >> 2;  // head owning channels gg*8..gg*8+7
  __shared__ float s_w[4 * 64];
  __shared__ int s_src[64];
  __shared__ float sf[4], sden[4];
  __shared__ float sacc[8][132];
  int beg = row_ofs[n], end = row_ofs[n + 1];
  float adn = adst[(size_t)n * 4 + h];
  float m_run = -1e30f, s_run = 0.f;
  float acc[8];
#pragma unroll
  for (int i = 0; i < 8; ++i) acc[i] = 0.f;

  for (int base = beg; base < end; base += 64) {
    int cnt = end - base; if (cnt > 64) cnt = 64;
    // ---- alpha phase ----
    float a0 = -1e30f, a1 = -1e30f;
    if (j < cnt) {
      int idx = base + j;
      float ae = upkh(recAE[(size_t)idx * 2 + (h >> 1)], h & 1);
      int sj = recSrc[idx];
      if (h == 0) s_src[j] = sj;
      float a = asrc[(size_t)sj * 4 + h] + adn + ae;
      a0 = (a > 0.f) ? a : NEG_SLOPE * a;
    }
    if (j + 32 < cnt) {
      int idx = base + j + 32;
      float ae = upkh(recAE[(size_t)idx * 2 + (h >> 1)], h & 1);
      int sj = recSrc[idx];
      if (h == 0) s_src[j + 32] = sj;
      float a = asrc[(size_t)sj * 4 + h] + adn + ae;
      a1 = (a > 0.f) ? a : NEG_SLOPE * a;
    }
    float cm = fmaxf(a0, a1);
#pragma unroll
    for (int off = 16; off; off >>= 1) cm = fmaxf(cm, __shfl_xor(cm, off, 32));
    float f = 1.f;
    if (cm > m_run) { f = expf(m_run - cm); s_run *= f; m_run = cm; }
    if (j == 0) sf[h] = f;
    float ex0 = (j < cnt) ? expf(a0 - m_run) : 0.f;
    float ex1 = (j + 32 < cnt) ? expf(a1 - m_run) : 0.f;
    s_w[h * 64 + j] = ex0;
    s_w[h * 64 + j + 32] = ex1;
    float se = ex0 + ex1;
#pragma unroll
    for (int off = 16; off; off >>= 1) se += __shfl_xor(se, off, 32);
    s_run += se;
    __syncthreads();
    // ---- accumulate phase: 8 edges in flight, 16B (8ch) per thread ----
    float ff = sf[hh];
    if (ff != 1.f) {
#pragma unroll
      for (int i = 0; i < 8; ++i) acc[i] *= ff;
    }
    for (int e2 = 0; e2 < cnt; e2 += 8) {
      int ed = e2 + e4;
      if (ed < cnt) {
        int sj = s_src[ed];
        float w = s_w[hh * 64 + ed];
        uint4 v = *(const uint4*)&xp[(size_t)sj * 128 + gg * 8];
        acc[0] += w * upkh(v.x, 0); acc[1] += w * upkh(v.x, 1);
        acc[2] += w * upkh(v.y, 0); acc[3] += w * upkh(v.y, 1);
        acc[4] += w * upkh(v.z, 0); acc[5] += w * upkh(v.z, 1);
        acc[6] += w * upkh(v.w, 0); acc[7] += w * upkh(v.w, 1);
      }
    }
    __syncthreads();
  }
  if (j == 0) sden[h] = s_run;
#pragma unroll
  for (int i = 0; i < 8; ++i) sacc[e4][gg * 8 + i] = acc[i];
  __syncthreads();
  float v = 0.f;
#pragma unroll
  for (int i = 0; i < 8; ++i) v += sacc[i][t];
  v = v / (sden[t >> 5] + 1e-16f) + bias[t];
  v = (v - rm[t]) * (g[t] * rsqrtf(rv[t] + BN_EPS)) + be[t];
  v = (v > 0.f) ? v : (expf(v) - 1.f);
  out[(size_t)n * 128 + t] = v;
}

// ---------------- layer 3 projection + alphas ----------------
__global__ __launch_bounds__(256) void xp3_k(const float* __restrict__ h2,
                                             const float* __restrict__ W3,
                                             const float* __restrict__ as3,
                                             const float* __restrict__ ad3,
                                             float* __restrict__ xp3,
                                             float* __restrict__ asrc3,
                                             float* __restrict__ adst3) {
  __shared__ float sW[256];
  int t = threadIdx.x;
  sW[t] = W3[t];
  __syncthreads();
  int n = blockIdx.x * 256 + t;
  if (n < NN) {
    const float4* row = (const float4*)(h2 + (size_t)n * 128);
    float y0 = 0.f, y1 = 0.f;
#pragma unroll
    for (int i = 0; i < 32; ++i) {
      float4 v = row[i];
      y0 += v.x * sW[(i * 4 + 0) * 2] + v.y * sW[(i * 4 + 1) * 2] +
            v.z * sW[(i * 4 + 2) * 2] + v.w * sW[(i * 4 + 3) * 2];
      y1 += v.x * sW[(i * 4 + 0) * 2 + 1] + v.y * sW[(i * 4 + 1) * 2 + 1] +
            v.z * sW[(i * 4 + 2) * 2 + 1] + v.w * sW[(i * 4 + 3) * 2 + 1];
    }
    xp3[n * 2] = y0;
    xp3[n * 2 + 1] = y1;
    asrc3[n] = y0 * as3[0] + y1 * as3[1];
    adst3[n] = y0 * ad3[0] + y1 * ad3[1];
  }
}

// ---------------- layer 3 aggregation: wave per node ----------------
__global__ __launch_bounds__(256) void agg2_k(const int* __restrict__ row_ofs,
                                              const float* __restrict__ rec3,
                                              const int* __restrict__ recSrc,
                                              const float* __restrict__ xp3,
                                              const float* __restrict__ asrc3,
                                              const float* __restrict__ adst3,
                                              const float* __restrict__ b3,
                                              float* __restrict__ out) {
  int t = threadIdx.x;
  int w = t >> 6, l = t & 63;
  int n = blockIdx.x * 4 + w;
  if (n >= NN) return;
  int beg = row_ofs[n], end = row_ofs[n + 1];
  float adn = adst3[n];
  float m = -1e30f, s = 0.f, a0 = 0.f, a1 = 0.f;
  for (int idx = beg + l; idx < end; idx += 64) {
    float aev = rec3[idx];
    int sj = recSrc[idx];
    float a = asrc3[sj] + adn + aev;
    a = (a > 0.f) ? a : NEG_SLOPE * a;
    if (a > m) {
      float f = expf(m - a);
      s *= f; a0 *= f; a1 *= f; m = a;
    }
    float ex = expf(a - m);
    s += ex;
    a0 += ex * xp3[sj * 2];
    a1 += ex * xp3[sj * 2 + 1];
  }
  float M = m;
#pragma unroll
  for (int off = 32; off; off >>= 1) M = fmaxf(M, __shfl_xor(M, off, 64));
  float f = expf(m - M);
  s *= f; a0 *= f; a1 *= f;
#pragma unroll
  for (int off = 32; off; off >>= 1) {
    s += __shfl_xor(s, off, 64);
    a0 += __shfl_xor(a0, off, 64);
    a1 += __shfl_xor(a1, off, 64);
  }
  if (l == 0) {
    float inv = 1.f / (s + 1e-16f);
    out[n * 2] = a0 * inv + b3[0];
    out[n * 2 + 1] = a1 * inv + b3[1];
  }
}

// ---------------- launcher ----------------
extern "C" void kernel_launch(void* const* d_in, const int* in_sizes, int n_in,
                              void* d_out, int out_size, void* d_ws, size_t ws_size,
                              hipStream_t stream) {
  const float* x   = (const float*)d_in[0];
  const int*   ei  = (const int*)d_in[1];
  const float* ea  = (const float*)d_in[2];
  const float* W1  = (const float*)d_in[3];
  const float* as1 = (const float*)d_in[4];
  const float* ad1 = (const float*)d_in[5];
  const float* We1 = (const float*)d_in[6];
  const float* ae1 = (const float*)d_in[7];
  const float* b1  = (const float*)d_in[8];
  const float* g1  = (const float*)d_in[9];
  const float* be1 = (const float*)d_in[10];
  const float* rm1 = (const float*)d_in[11];
  const float* rv1 = (const float*)d_in[12];
  const float* W2  = (const float*)d_in[13];
  const float* as2 = (const float*)d_in[14];
  const float* ad2 = (const float*)d_in[15];
  const float* We2 = (const float*)d_in[16];
  const float* ae2 = (const float*)d_in[17];
  const float* b2  = (const float*)d_in[18];
  const float* g2  = (const float*)d_in[19];
  const float* be2 = (const float*)d_in[20];
  const float* rm2 = (const float*)d_in[21];
  const float* rv2 = (const float*)d_in[22];
  const float* W3  = (const float*)d_in[23];
  const float* as3 = (const float*)d_in[24];
  const float* ad3 = (const float*)d_in[25];
  const float* We3 = (const float*)d_in[26];
  const float* ae3 = (const float*)d_in[27];
  const float* b3  = (const float*)d_in[28];

  const int* srcA = ei;
  const int* dstA = ei + EE;

  char* p = (char*)d_ws;
  auto alloc = [&](size_t bytes) -> void* {
    void* r = (void*)p;
    p += (bytes + 255) & ~(size_t)255;
    return r;
  };
  uint2* recAE1 = (uint2*)alloc(sizeof(uint2) * (size_t)ETOT);
  uint2* recAE2 = (uint2*)alloc(sizeof(uint2) * (size_t)ETOT);
  float* rec3   = (float*)alloc(sizeof(float) * (size_t)ETOT);
  int*   recSrc = (int*)alloc(sizeof(int) * (size_t)ETOT);
  __half* xp    = (__half*)alloc(sizeof(__half) * (size_t)NN * 128);
  float* hbuf   = (float*)alloc(sizeof(float) * (size_t)NN * 128);
  float* Mbuf   = (float*)alloc(sizeof(float) * 144);
  float* meanp  = (float*)alloc(sizeof(float) * (size_t)FILL_BLOCKS * 16);
  float* asl    = (float*)alloc(sizeof(float) * 12);
  float* asrc   = (float*)alloc(sizeof(float) * (size_t)NN * 4);
  float* adst   = (float*)alloc(sizeof(float) * (size_t)NN * 4);
  float* xp3    = (float*)alloc(sizeof(float) * (size_t)NN * 2);
  float* asrc3  = (float*)alloc(sizeof(float) * (size_t)NN);
  float* adst3  = (float*)alloc(sizeof(float) * (size_t)NN);
  int* deg      = (int*)alloc(sizeof(int) * (size_t)NN);
  int* part     = (int*)alloc(sizeof(int) * 256);
  int* row_ofs  = (int*)alloc(sizeof(int) * (size_t)(NN + 1));
  int* cursor   = (int*)alloc(sizeof(int) * (size_t)NN);

  hipMemsetAsync(deg, 0, NN * sizeof(int), stream);

  compute_M_k<<<1, 64, 0, stream>>>(We1, ae1, We2, ae2, We3, ae3, Mbuf);
  deg_k<<<(EE + 255) / 256, 256, 0, stream>>>(dstA, deg);
  scan_part_k<<<NB_SCAN, 256, 0, stream>>>(deg, part);
  scan_base_k<<<1, 256, 0, stream>>>(part);
  scan_fill_k<<<NB_SCAN, 256, 0, stream>>>(deg, part, row_ofs, cursor);
  fill_k<<<FILL_BLOCKS, 256, 0, stream>>>(srcA, dstA, ea, Mbuf, cursor,
                                          recAE1, recAE2, rec3, recSrc, meanp);
  selfloop_k<<<1, 256, 0, stream>>>(meanp, Mbuf, asl);
  slrec_k<<<(NN + 255) / 256, 256, 0, stream>>>(row_ofs, asl, recAE1, recAE2, rec3, recSrc);

  // ---- layer 1 ----
  gemm128a_k<<<dim3((NN + 63) / 64, 2), 256, 0, stream>>>(x, W1, as1, ad1, xp, asrc, adst, NN);
  agg128_k<<<NN, 128, 0, stream>>>(row_ofs, (const unsigned*)recAE1, recSrc, xp,
                                   asrc, adst, b1, g1, be1, rm1, rv1, hbuf);
  // ---- layer 2 ----
  gemm128a_k<<<dim3((NN + 63) / 64, 2), 256, 0, stream>>>(hbuf, W2, as2, ad2, xp, asrc, adst, NN);
  agg128_k<<<NN, 128, 0, stream>>>(row_ofs, (const unsigned*)recAE2, recSrc, xp,
                                   asrc, adst, b2, g2, be2, rm2, rv2, hbuf);
  // ---- layer 3 ----
  xp3_k<<<(NN + 255) / 256, 256, 0, stream>>>(hbuf, W3, as3, ad3, xp3, asrc3, adst3);
  agg2_k<<<(NN + 3) / 4, 256, 0, stream>>>(row_ofs, rec3, recSrc, xp3, asrc3, adst3,
                                           b3, (float*)d_out);
}